// Round 4
// baseline (599.626 us; speedup 1.0000x reference)
//
#include <hip/hip_runtime.h>
#include <stdint.h>

// B=4096, IN=1024, L0=2048, L1=1024, H=128, NT=512, T=0.1, EPS=1e-5

typedef __attribute__((ext_vector_type(8))) __bf16 bf16x8;
typedef __attribute__((ext_vector_type(4))) float f32x4;

__device__ __forceinline__ unsigned short f2bf(float f) {
  unsigned int u = __float_as_uint(f);
  unsigned int r = (u + 0x7fffu + ((u >> 16) & 1u)) >> 16;  // RNE
  return (unsigned short)r;
}
__device__ __forceinline__ float bf2f(unsigned short h) {
  return __uint_as_float(((unsigned int)h) << 16);
}

__device__ __forceinline__ void gll16(const void* g, void* l) {
  __builtin_amdgcn_global_load_lds(
      (const __attribute__((address_space(1))) unsigned int*)g,
      (__attribute__((address_space(3))) unsigned int*)l, 16, 0, 0);
}

// ---------------- f32 -> split bf16 (hi, lo), 4 elems/thread ----------------
__global__ void kconvert_split4(const float4* __restrict__ in, ushort4* __restrict__ hi,
                                ushort4* __restrict__ lo, int n4) {
  int i = blockIdx.x * blockDim.x + threadIdx.x;
  if (i < n4) {
    float4 v = in[i];
    ushort4 h, l;
    h.x = f2bf(v.x); l.x = f2bf(v.x - bf2f(h.x));
    h.y = f2bf(v.y); l.y = f2bf(v.y - bf2f(h.y));
    h.z = f2bf(v.z); l.z = f2bf(v.z - bf2f(h.z));
    h.w = f2bf(v.w); l.w = f2bf(v.w - bf2f(h.w));
    hi[i] = h; lo[i] = l;
  }
}

// ---------------- transpose + split convert: in[R][C] f32 -> out[C][R] split bf16 ----------------
__global__ void ktranspose_split(const float* __restrict__ in, unsigned short* __restrict__ ohi,
                                 unsigned short* __restrict__ olo, int R, int C) {
  __shared__ unsigned short th[32][33];
  __shared__ unsigned short tl[32][33];
  int c0 = blockIdx.x * 32, r0 = blockIdx.y * 32;
  int tx = threadIdx.x & 31, ty = threadIdx.x >> 5;  // 32 x 8
#pragma unroll
  for (int i = 0; i < 32; i += 8) {
    float v = in[(size_t)(r0 + ty + i) * C + c0 + tx];
    unsigned short h = f2bf(v);
    th[ty + i][tx] = h;
    tl[ty + i][tx] = f2bf(v - bf2f(h));
  }
  __syncthreads();
#pragma unroll
  for (int i = 0; i < 32; i += 8) {
    ohi[(size_t)(c0 + ty + i) * R + r0 + tx] = th[tx][ty + i];
    olo[(size_t)(c0 + ty + i) * R + r0 + tx] = tl[tx][ty + i];
  }
}

// ============ split-bf16 3-pass GEMM, 256x128 block tile, wave tile 128x64 ============
// C[M][N] = (Ah+Al)@(Bh+Bl)^T (+bias), dropping Al*Bl. grid=(M/256, N/128, splits).
// 96 MFMA per wave per K-step (covers global_load_lds latency issued before the cluster).
// bnps!=null -> also emit BN column partials (one stripe per blockIdx.x).
__global__ __launch_bounds__(256, 2) void kgemm3p256(
    const unsigned short* __restrict__ Ah, const unsigned short* __restrict__ Al,
    const unsigned short* __restrict__ Bh, const unsigned short* __restrict__ Bl,
    const float* __restrict__ bias, float* __restrict__ C, int N, int K, int kLen,
    float* __restrict__ bnps, float* __restrict__ bnpq) {
  __shared__ unsigned short As[2][8192];  // [hi|lo][256 rows x 32 k]  32KB
  __shared__ unsigned short Bs[2][4096];  // [hi|lo][128 rows x 32 k]  16KB
  __shared__ float sred[2][2][128];
  int tid = threadIdx.x;
  int lane = tid & 63;
  int wave = tid >> 6;
  int wm = wave >> 1, wn = wave & 1;  // 2M x 2N waves
  int rowBase = blockIdx.x * 256;
  int colBase = blockIdx.y * 128;
  int kOff = blockIdx.z * kLen;
  C += (size_t)blockIdx.z * gridDim.x * 256 * N;  // split-K partial stripe

  f32x4 acc[8][4];
#pragma unroll
  for (int i = 0; i < 8; i++)
#pragma unroll
    for (int j = 0; j < 4; j++) acc[i][j] = (f32x4){0.f, 0.f, 0.f, 0.f};

  int r4 = tid >> 2;       // 0..63
  int kc = (tid & 3) * 8;  // 0,8,16,24
  int lr = lane & 15;
  int lk = (lane >> 4) * 8;

  const unsigned short* Ah0 = Ah + (size_t)(rowBase + r4) * K + kOff + kc;
  const unsigned short* Al0 = Al + (size_t)(rowBase + r4) * K + kOff + kc;
  const unsigned short* Bh0 = Bh + (size_t)(colBase + r4) * K + kOff + kc;
  const unsigned short* Bl0 = Bl + (size_t)(colBase + r4) * K + kOff + kc;
  size_t rstep = (size_t)64 * K;
  char* AsD = (char*)As + tid * 16;
  char* BsD = (char*)Bs + tid * 16;

  auto STAGE = [&](int k0) {
    // A hi: 4x64 rows; A lo; B hi: 2x64 rows; B lo  (12 x global_load_lds dwordx4)
    gll16(Ah0 + k0, AsD);
    gll16(Ah0 + k0 + rstep, AsD + 4096);
    gll16(Ah0 + k0 + 2 * rstep, AsD + 8192);
    gll16(Ah0 + k0 + 3 * rstep, AsD + 12288);
    gll16(Al0 + k0, AsD + 16384);
    gll16(Al0 + k0 + rstep, AsD + 20480);
    gll16(Al0 + k0 + 2 * rstep, AsD + 24576);
    gll16(Al0 + k0 + 3 * rstep, AsD + 28672);
    gll16(Bh0 + k0, BsD);
    gll16(Bh0 + k0 + rstep, BsD + 4096);
    gll16(Bl0 + k0, BsD + 8192);
    gll16(Bl0 + k0 + rstep, BsD + 12288);
  };

  STAGE(0);
  __syncthreads();  // compiler drains vmcnt before barrier

  int nk = kLen >> 5;
  for (int kt = 0; kt < nk; ++kt) {
    // 1) all fragments LDS -> regs (24 ds_read_b128)
    bf16x8 ah[8], al[8], bh[4], bl[4];
#pragma unroll
    for (int mi = 0; mi < 8; mi++) {
      ah[mi] = *(const bf16x8*)&As[0][(wm * 128 + mi * 16 + lr) * 32 + lk];
      al[mi] = *(const bf16x8*)&As[1][(wm * 128 + mi * 16 + lr) * 32 + lk];
    }
#pragma unroll
    for (int ni = 0; ni < 4; ni++) {
      bh[ni] = *(const bf16x8*)&Bs[0][(wn * 64 + ni * 16 + lr) * 32 + lk];
      bl[ni] = *(const bf16x8*)&Bs[1][(wn * 64 + ni * 16 + lr) * 32 + lk];
    }
    __syncthreads();  // all waves done reading LDS

    // 2) issue next tile staging now; latency hides under 96 MFMAs (~470cy)
    if (kt + 1 < nk) STAGE((kt + 1) << 5);

    // 3) MFMA cluster
#pragma unroll
    for (int mi = 0; mi < 8; mi++)
#pragma unroll
      for (int ni = 0; ni < 4; ni++) {
        acc[mi][ni] = __builtin_amdgcn_mfma_f32_16x16x32_bf16(ah[mi], bh[ni], acc[mi][ni], 0, 0, 0);
        acc[mi][ni] = __builtin_amdgcn_mfma_f32_16x16x32_bf16(ah[mi], bl[ni], acc[mi][ni], 0, 0, 0);
      }
#pragma unroll
    for (int mi = 0; mi < 8; mi++)
#pragma unroll
      for (int ni = 0; ni < 4; ni++)
        acc[mi][ni] = __builtin_amdgcn_mfma_f32_16x16x32_bf16(al[mi], bh[ni], acc[mi][ni], 0, 0, 0);
    __syncthreads();  // staging complete (vmcnt drained) before next tile's reads
  }

  int lg = lane >> 4;
  float s[4] = {0.f, 0.f, 0.f, 0.f}, q[4] = {0.f, 0.f, 0.f, 0.f};
#pragma unroll
  for (int mi = 0; mi < 8; mi++)
#pragma unroll
    for (int ni = 0; ni < 4; ni++) {
      int col = colBase + wn * 64 + ni * 16 + lr;
      float bv = bias ? bias[col] : 0.0f;
#pragma unroll
      for (int j = 0; j < 4; j++) {
        int row = rowBase + wm * 128 + mi * 16 + lg * 4 + j;
        float v = acc[mi][ni][j] + bv;
        C[(size_t)row * N + col] = v;
        s[ni] += v;
        q[ni] += v * v;
      }
    }
  if (bnps) {
#pragma unroll
    for (int ni = 0; ni < 4; ni++) {
      s[ni] += __shfl_xor(s[ni], 16); s[ni] += __shfl_xor(s[ni], 32);
      q[ni] += __shfl_xor(q[ni], 16); q[ni] += __shfl_xor(q[ni], 32);
    }
    if (lg == 0) {
#pragma unroll
      for (int ni = 0; ni < 4; ni++) {
        sred[wm][0][wn * 64 + ni * 16 + lr] = s[ni];
        sred[wm][1][wn * 64 + ni * 16 + lr] = q[ni];
      }
    }
    __syncthreads();
    if (tid < 128) {
      bnps[(size_t)blockIdx.x * N + colBase + tid] = sred[0][0][tid] + sred[1][0][tid];
      bnpq[(size_t)blockIdx.x * N + colBase + tid] = sred[0][1][tid] + sred[1][1][tid];
    }
  }
}

// ---------------- split-bf16 3-pass GEMM, 128x128 tile (small-N layers) ----------------
__global__ __launch_bounds__(256) void kgemm3p(
    const unsigned short* __restrict__ Ah, const unsigned short* __restrict__ Al,
    const unsigned short* __restrict__ Bh, const unsigned short* __restrict__ Bl,
    const float* __restrict__ bias, float* __restrict__ C, int N, int K, int kLen,
    const float* __restrict__ diag) {
  __shared__ unsigned short As[2][4096];
  __shared__ unsigned short Bs[2][4096];
  int tid = threadIdx.x;
  int lane = tid & 63;
  int wave = tid >> 6;
  int wm = wave >> 1, wn = wave & 1;
  int rowBase = blockIdx.x * 128;
  int colBase = blockIdx.y * 128;
  int kOff = blockIdx.z * kLen;
  C += (size_t)blockIdx.z * gridDim.x * 128 * N;

  f32x4 acc[4][4];
#pragma unroll
  for (int i = 0; i < 4; i++)
#pragma unroll
    for (int j = 0; j < 4; j++) acc[i][j] = (f32x4){0.f, 0.f, 0.f, 0.f};

  int r4 = tid >> 2;
  int kc = (tid & 3) * 8;
  int lr = lane & 15;
  int lk = (lane >> 4) * 8;

  const unsigned short* Ah0 = Ah + (size_t)(rowBase + r4) * K + kOff + kc;
  const unsigned short* Al0 = Al + (size_t)(rowBase + r4) * K + kOff + kc;
  const unsigned short* Bh0 = Bh + (size_t)(colBase + r4) * K + kOff + kc;
  const unsigned short* Bl0 = Bl + (size_t)(colBase + r4) * K + kOff + kc;
  size_t rstep = (size_t)64 * K;
  char* AsD = (char*)As + tid * 16;
  char* BsD = (char*)Bs + tid * 16;

  gll16(Ah0, AsD);        gll16(Ah0 + rstep, AsD + 4096);
  gll16(Al0, AsD + 8192); gll16(Al0 + rstep, AsD + 12288);
  gll16(Bh0, BsD);        gll16(Bh0 + rstep, BsD + 4096);
  gll16(Bl0, BsD + 8192); gll16(Bl0 + rstep, BsD + 12288);
  __syncthreads();

  int nk = kLen >> 5;
  for (int kt = 0; kt < nk; ++kt) {
    bf16x8 ah[4], al[4], bh[4], bl[4];
#pragma unroll
    for (int mi = 0; mi < 4; mi++) {
      ah[mi] = *(const bf16x8*)&As[0][(wm * 64 + mi * 16 + lr) * 32 + lk];
      al[mi] = *(const bf16x8*)&As[1][(wm * 64 + mi * 16 + lr) * 32 + lk];
      bh[mi] = *(const bf16x8*)&Bs[0][(wn * 64 + mi * 16 + lr) * 32 + lk];
      bl[mi] = *(const bf16x8*)&Bs[1][(wn * 64 + mi * 16 + lr) * 32 + lk];
    }
    __syncthreads();
    if (kt + 1 < nk) {
      int k0 = (kt + 1) << 5;
      gll16(Ah0 + k0, AsD);        gll16(Ah0 + k0 + rstep, AsD + 4096);
      gll16(Al0 + k0, AsD + 8192); gll16(Al0 + k0 + rstep, AsD + 12288);
      gll16(Bh0 + k0, BsD);        gll16(Bh0 + k0 + rstep, BsD + 4096);
      gll16(Bl0 + k0, BsD + 8192); gll16(Bl0 + k0 + rstep, BsD + 12288);
    }
#pragma unroll
    for (int mi = 0; mi < 4; mi++)
#pragma unroll
      for (int ni = 0; ni < 4; ni++) {
        acc[mi][ni] = __builtin_amdgcn_mfma_f32_16x16x32_bf16(ah[mi], bh[ni], acc[mi][ni], 0, 0, 0);
        acc[mi][ni] = __builtin_amdgcn_mfma_f32_16x16x32_bf16(ah[mi], bl[ni], acc[mi][ni], 0, 0, 0);
        acc[mi][ni] = __builtin_amdgcn_mfma_f32_16x16x32_bf16(al[mi], bh[ni], acc[mi][ni], 0, 0, 0);
      }
    __syncthreads();
  }

  int lg = lane >> 4;
#pragma unroll
  for (int mi = 0; mi < 4; mi++)
#pragma unroll
    for (int ni = 0; ni < 4; ni++) {
      int col = colBase + wn * 64 + ni * 16 + lr;
      float bv = bias ? bias[col] : 0.0f;
      float dg = diag ? diag[col] : 0.0f;
#pragma unroll
      for (int j = 0; j < 4; j++) {
        int row = rowBase + wm * 64 + mi * 16 + lg * 4 + j;
        float v = acc[mi][ni][j] + bv;
        if (diag) v = fminf(fmaxf(fabsf(v) * dg, 1e-10f), 1e7f);
        C[(size_t)row * N + col] = v;
      }
    }
}

// ---------------- single-pass bf16 GEMM (reconstruction), register-pipelined ----------------
__global__ __launch_bounds__(256) void kgemm(
    const unsigned short* __restrict__ A, const unsigned short* __restrict__ BT,
    float* __restrict__ C, int N, int K) {
  __shared__ unsigned short As[4096];
  __shared__ unsigned short Bs[4096];
  int tid = threadIdx.x;
  int lane = tid & 63;
  int wave = tid >> 6;
  int wm = wave >> 1, wn = wave & 1;
  int rowBase = blockIdx.x * 128;
  int colBase = blockIdx.y * 128;

  f32x4 acc[4][4];
#pragma unroll
  for (int i = 0; i < 4; i++)
#pragma unroll
    for (int j = 0; j < 4; j++) acc[i][j] = (f32x4){0.f, 0.f, 0.f, 0.f};

  int r4 = tid >> 2;
  int kc = (tid & 3) * 8;
  int lr = lane & 15;
  int lk = (lane >> 4) * 8;

  const unsigned short* A0 = A + (size_t)(rowBase + r4) * K + kc;
  const unsigned short* B0 = BT + (size_t)(colBase + r4) * K + kc;
  size_t rstep = (size_t)64 * K;
  char* AsD = (char*)As + tid * 16;
  char* BsD = (char*)Bs + tid * 16;

  gll16(A0, AsD); gll16(A0 + rstep, AsD + 4096);
  gll16(B0, BsD); gll16(B0 + rstep, BsD + 4096);
  __syncthreads();

  int nk = K >> 5;
  for (int kt = 0; kt < nk; ++kt) {
    bf16x8 af[4], bfr[4];
#pragma unroll
    for (int mi = 0; mi < 4; mi++) {
      af[mi] = *(const bf16x8*)&As[(wm * 64 + mi * 16 + lr) * 32 + lk];
      bfr[mi] = *(const bf16x8*)&Bs[(wn * 64 + mi * 16 + lr) * 32 + lk];
    }
    __syncthreads();
    if (kt + 1 < nk) {
      int k0 = (kt + 1) << 5;
      gll16(A0 + k0, AsD); gll16(A0 + k0 + rstep, AsD + 4096);
      gll16(B0 + k0, BsD); gll16(B0 + k0 + rstep, BsD + 4096);
    }
#pragma unroll
    for (int mi = 0; mi < 4; mi++)
#pragma unroll
      for (int ni = 0; ni < 4; ni++)
        acc[mi][ni] = __builtin_amdgcn_mfma_f32_16x16x32_bf16(af[mi], bfr[ni], acc[mi][ni], 0, 0, 0);
    __syncthreads();
  }

  int lg = lane >> 4;
#pragma unroll
  for (int mi = 0; mi < 4; mi++)
#pragma unroll
    for (int ni = 0; ni < 4; ni++) {
      int col = colBase + wn * 64 + ni * 16 + lr;
#pragma unroll
      for (int j = 0; j < 4; j++) {
        int row = rowBase + wm * 64 + mi * 16 + lg * 4 + j;
        C[(size_t)row * N + col] = acc[mi][ni][j];
      }
    }
}

// ---- split-K combine + bias + BN column partials (one stripe of 128 rows per block.y) ----
__global__ void kcombine_bn(const float* __restrict__ Cp, const float* __restrict__ bias,
                            float* __restrict__ y, float* __restrict__ ps, float* __restrict__ pq,
                            int N, int splits, int splitStride) {
  int c = blockIdx.x * 128 + threadIdx.x;
  int r0 = blockIdx.y * 128;
  float bv = bias[c];
  float s = 0.f, q = 0.f;
  for (int r = r0; r < r0 + 128; ++r) {
    float v = bv;
    for (int z = 0; z < splits; ++z) v += Cp[(size_t)z * splitStride + (size_t)r * N + c];
    y[(size_t)r * N + c] = v;
    s += v;
    q += v * v;
  }
  ps[blockIdx.y * N + c] = s;
  pq[blockIdx.y * N + c] = q;
}

__global__ void kbn_final(const float* __restrict__ ps, const float* __restrict__ pq,
                          const float* __restrict__ g, const float* __restrict__ b,
                          float* __restrict__ scale, float* __restrict__ shift, int N,
                          int stripes) {
  int c = blockIdx.x * blockDim.x + threadIdx.x;
  if (c >= N) return;
  float s = 0.f, q = 0.f;
  for (int i = 0; i < stripes; ++i) {
    s += ps[i * N + c];
    q += pq[i * N + c];
  }
  float m = s * (1.0f / 4096.0f);
  float var = q * (1.0f / 4096.0f) - m * m;
  float sc = g[c] * rsqrtf(var + 1e-5f);
  scale[c] = sc;
  shift[c] = b[c] - m * sc;
}

// BN apply + ReLU + split-bf16 output, 4 elems/thread
__global__ void kbn_apply_split4(const float4* __restrict__ y, const float* __restrict__ scale,
                                 const float* __restrict__ shift, ushort4* __restrict__ hhi,
                                 ushort4* __restrict__ hlo, int mask) {
  int i = blockIdx.x * blockDim.x + threadIdx.x;
  int c0 = (i << 2) & mask;
  float4 v = y[i];
  ushort4 h, l;
  float t;
  t = v.x * scale[c0] + shift[c0];         t = t > 0.f ? t : 0.f; h.x = f2bf(t); l.x = f2bf(t - bf2f(h.x));
  t = v.y * scale[c0 + 1] + shift[c0 + 1]; t = t > 0.f ? t : 0.f; h.y = f2bf(t); l.y = f2bf(t - bf2f(h.y));
  t = v.z * scale[c0 + 2] + shift[c0 + 2]; t = t > 0.f ? t : 0.f; h.z = f2bf(t); l.z = f2bf(t - bf2f(h.z));
  t = v.w * scale[c0 + 3] + shift[c0 + 3]; t = t > 0.f ? t : 0.f; h.w = f2bf(t); l.w = f2bf(t - bf2f(h.w));
  hhi[i] = h;
  hlo[i] = l;
}

// ---------------- decoder normalization ----------------
__global__ void kdec(const float* __restrict__ dec_w, float* __restrict__ decode,
                     unsigned short* __restrict__ decT, float* __restrict__ diag) {
  int h = blockIdx.x, tx = threadIdx.x;
  __shared__ float red[256];
  float s = 0.f;
  for (int i = tx; i < 1024; i += 256) s += dec_w[h * 1024 + i];
  red[tx] = s;
  __syncthreads();
  for (int k = 128; k > 0; k >>= 1) {
    if (tx < k) red[tx] += red[tx + k];
    __syncthreads();
  }
  float d = fabsf(red[0]);
  if (tx == 0) diag[h] = d;
  float inv = 1.0f / d;
  for (int i = tx; i < 1024; i += 256) {
    float v = fabsf(dec_w[h * 1024 + i]) * inv;
    decode[h * 1024 + i] = v;
    decT[i * 128 + h] = f2bf(v);
  }
}

// ---------------- Poisson rsample with early exit ----------------
__global__ __launch_bounds__(256) void kpoisson(const float* __restrict__ u,
                                                const float* __restrict__ rate,
                                                float* __restrict__ samples,
                                                unsigned short* __restrict__ sb) {
  int tid = blockIdx.x * 256 + threadIdx.x;
  int h = tid & 127;
  int b = tid >> 7;
  float r = rate[tid];
  float inv = 1.0f / r;
  const float* up = u + (size_t)b * (512 * 128) + h;
  float t = 0.f, s = 0.f;
  for (int nt = 0; nt < 512; ++nt) {
    float uv = up[(size_t)nt * 128];
    t += (-__logf(uv)) * inv;
    float z = (t - 1.0f) * 10.0f;
    s += __frcp_rn(1.0f + __expf(z));
    if (t > 4.0f) break;
  }
  samples[tid] = s;
  sb[tid] = f2bf(s);
}

extern "C" void kernel_launch(void* const* d_in, const int* in_sizes, int n_in,
                              void* d_out, int out_size, void* d_ws, size_t ws_size,
                              hipStream_t stream) {
  const float* x = (const float*)d_in[0];
  const float* u = (const float*)d_in[1];
  const float* w1 = (const float*)d_in[2];
  const float* b1 = (const float*)d_in[3];
  const float* g1 = (const float*)d_in[4];
  const float* bb1 = (const float*)d_in[5];
  const float* w2 = (const float*)d_in[6];
  const float* b2 = (const float*)d_in[7];
  const float* g2 = (const float*)d_in[8];
  const float* bb2 = (const float*)d_in[9];
  const float* w3 = (const float*)d_in[10];
  const float* b3 = (const float*)d_in[11];
  const float* g3 = (const float*)d_in[12];
  const float* bb3 = (const float*)d_in[13];
  const float* w4 = (const float*)d_in[14];
  const float* b4 = (const float*)d_in[15];
  const float* dw = (const float*)d_in[16];

  float* out = (float*)d_out;
  float* out_xrec = out;            // [4096][1024]
  float* out_samp = out + 4194304;  // [4096][128]
  float* out_rate = out + 4718592;  // [4096][128]
  float* out_dec = out + 5242880;   // [128][1024]

  char* w = (char*)d_ws;
  unsigned short* xhi = (unsigned short*)w;  w += 8388608;   // [4096][1024]
  unsigned short* xlo = (unsigned short*)w;  w += 8388608;
  unsigned short* w1th = (unsigned short*)w; w += 4194304;   // [2048][1024]
  unsigned short* w1tl = (unsigned short*)w; w += 4194304;
  unsigned short* w2th = (unsigned short*)w; w += 4194304;   // [1024][2048]
  unsigned short* w2tl = (unsigned short*)w; w += 4194304;
  unsigned short* w3th = (unsigned short*)w; w += 262144;    // [128][1024]
  unsigned short* w3tl = (unsigned short*)w; w += 262144;
  unsigned short* w4th = (unsigned short*)w; w += 32768;     // [128][128]
  unsigned short* w4tl = (unsigned short*)w; w += 32768;
  float* y = (float*)w;             w += 33554432;           // y1 [4096][2048], reused as y2
  unsigned short* h1h = (unsigned short*)w; w += 16777216;   // [4096][2048]
  unsigned short* h1l = (unsigned short*)w; w += 16777216;
  unsigned short* h2h = (unsigned short*)w; w += 8388608;    // [4096][1024]
  unsigned short* h2l = (unsigned short*)w; w += 8388608;
  unsigned short* h3h = (unsigned short*)w; w += 1048576;    // [4096][128]
  unsigned short* h3l = (unsigned short*)w; w += 1048576;
  float* y3 = (float*)w;            w += 2097152;            // [4096][128]
  float* Cp = (float*)w;            w += 33554432;           // split-K partials (<=32MB)
  unsigned short* sb = (unsigned short*)w; w += 1048576;     // samples bf16
  unsigned short* dct = (unsigned short*)w; w += 262144;     // decode^T bf16 [1024][128]
  float* diag = (float*)w;          w += 1024;
  float* ps = (float*)w;            w += 262144;             // [<=32][N<=2048]
  float* pq = (float*)w;            w += 262144;
  float* scale = (float*)w;         w += 8192;
  float* shift = (float*)w;         w += 8192;

  // --- prep ---
  kconvert_split4<<<4096, 256, 0, stream>>>((const float4*)x, (ushort4*)xhi, (ushort4*)xlo, 1048576);
  ktranspose_split<<<dim3(64, 32), 256, 0, stream>>>(w1, w1th, w1tl, 1024, 2048);
  ktranspose_split<<<dim3(32, 64), 256, 0, stream>>>(w2, w2th, w2tl, 2048, 1024);
  ktranspose_split<<<dim3(4, 32), 256, 0, stream>>>(w3, w3th, w3tl, 1024, 128);
  ktranspose_split<<<dim3(4, 4), 256, 0, stream>>>(w4, w4th, w4tl, 128, 128);
  kdec<<<128, 256, 0, stream>>>(dw, out_dec, dct, diag);

  // --- encoder layer 1: 256x128 tiles, BN partials fused ---
  kgemm3p256<<<dim3(16, 16), 256, 0, stream>>>(xhi, xlo, w1th, w1tl, b1, y, 2048, 1024, 1024,
                                               ps, pq);
  kbn_final<<<8, 256, 0, stream>>>(ps, pq, g1, bb1, scale, shift, 2048, 16);
  kbn_apply_split4<<<8192, 256, 0, stream>>>((const float4*)y, scale, shift, (ushort4*)h1h,
                                             (ushort4*)h1l, 2047);

  // --- encoder layer 2: 256x128 tiles, split-K=2 (256 blocks), combine+BN fused ---
  kgemm3p256<<<dim3(16, 8, 2), 256, 0, stream>>>(h1h, h1l, w2th, w2tl, nullptr, Cp, 1024, 2048,
                                                 1024, nullptr, nullptr);
  kcombine_bn<<<dim3(8, 32), 128, 0, stream>>>(Cp, b2, y, ps, pq, 1024, 2, 4194304);
  kbn_final<<<4, 256, 0, stream>>>(ps, pq, g2, bb2, scale, shift, 1024, 32);
  kbn_apply_split4<<<4096, 256, 0, stream>>>((const float4*)y, scale, shift, (ushort4*)h2h,
                                             (ushort4*)h2l, 1023);

  // --- encoder layer 3: 128x128 tiles, split-K=8 (256 blocks), combine+BN fused ---
  kgemm3p<<<dim3(32, 1, 8), 256, 0, stream>>>(h2h, h2l, w3th, w3tl, nullptr, Cp, 128, 1024, 128,
                                              nullptr);
  kcombine_bn<<<dim3(1, 32), 128, 0, stream>>>(Cp, b3, y3, ps, pq, 128, 8, 524288);
  kbn_final<<<1, 128, 0, stream>>>(ps, pq, g3, bb3, scale, shift, 128, 32);
  kbn_apply_split4<<<512, 256, 0, stream>>>((const float4*)y3, scale, shift, (ushort4*)h3h,
                                            (ushort4*)h3l, 127);

  // --- lambda head + rate (fused epilogue) ---
  kgemm3p<<<dim3(32, 1), 256, 0, stream>>>(h3h, h3l, w4th, w4tl, b4, out_rate, 128, 128, 128,
                                           diag);

  // --- Poisson rsample ---
  kpoisson<<<2048, 256, 0, stream>>>(u, out_rate, out_samp, sb);

  // --- reconstruction ---
  kgemm<<<dim3(32, 8), 256, 0, stream>>>(sb, dct, out_xrec, 1024, 128);
}

// Round 5
// 558.143 us; speedup vs baseline: 1.0743x; 1.0743x over previous
//
#include <hip/hip_runtime.h>
#include <stdint.h>

// B=4096, IN=1024, L0=2048, L1=1024, H=128, NT=512, T=0.1, EPS=1e-5

typedef __attribute__((ext_vector_type(8))) __bf16 bf16x8;
typedef __attribute__((ext_vector_type(4))) float f32x4;

__device__ __forceinline__ unsigned short f2bf(float f) {
  unsigned int u = __float_as_uint(f);
  unsigned int r = (u + 0x7fffu + ((u >> 16) & 1u)) >> 16;  // RNE
  return (unsigned short)r;
}
__device__ __forceinline__ float bf2f(unsigned short h) {
  return __uint_as_float(((unsigned int)h) << 16);
}

__device__ __forceinline__ void gll16(const void* g, void* l) {
  __builtin_amdgcn_global_load_lds(
      (const __attribute__((address_space(1))) unsigned int*)g,
      (__attribute__((address_space(3))) unsigned int*)l, 16, 0, 0);
}

// ---------------- f32 -> split bf16 (hi, lo), 4 elems/thread ----------------
__global__ void kconvert_split4(const float4* __restrict__ in, ushort4* __restrict__ hi,
                                ushort4* __restrict__ lo, int n4) {
  int i = blockIdx.x * blockDim.x + threadIdx.x;
  if (i < n4) {
    float4 v = in[i];
    ushort4 h, l;
    h.x = f2bf(v.x); l.x = f2bf(v.x - bf2f(h.x));
    h.y = f2bf(v.y); l.y = f2bf(v.y - bf2f(h.y));
    h.z = f2bf(v.z); l.z = f2bf(v.z - bf2f(h.z));
    h.w = f2bf(v.w); l.w = f2bf(v.w - bf2f(h.w));
    hi[i] = h; lo[i] = l;
  }
}

// ---------------- transpose + split convert: in[R][C] f32 -> out[C][R] split bf16 ----------------
__global__ void ktranspose_split(const float* __restrict__ in, unsigned short* __restrict__ ohi,
                                 unsigned short* __restrict__ olo, int R, int C) {
  __shared__ unsigned short th[32][33];
  __shared__ unsigned short tl[32][33];
  int c0 = blockIdx.x * 32, r0 = blockIdx.y * 32;
  int tx = threadIdx.x & 31, ty = threadIdx.x >> 5;  // 32 x 8
#pragma unroll
  for (int i = 0; i < 32; i += 8) {
    float v = in[(size_t)(r0 + ty + i) * C + c0 + tx];
    unsigned short h = f2bf(v);
    th[ty + i][tx] = h;
    tl[ty + i][tx] = f2bf(v - bf2f(h));
  }
  __syncthreads();
#pragma unroll
  for (int i = 0; i < 32; i += 8) {
    ohi[(size_t)(c0 + ty + i) * R + r0 + tx] = th[tx][ty + i];
    olo[(size_t)(c0 + ty + i) * R + r0 + tx] = tl[tx][ty + i];
  }
}

// ---------------- split-bf16 3-pass MFMA GEMM, register-pipelined, 128x128 tile ----------------
// C[M][N] = (Ah+Al)[M][K] @ (Bh+Bl)[N][K]^T (+bias), dropping Al*Bl.
// grid = (M/128, N/128, splits). kOff = blockIdx.z*kLen.
// Epilogues: diag!=null -> rate mode; bnps!=null -> BN column partials.
// NOTE: acc[4][4] (64 VGPR) + 16 frags (64 VGPR) fits without spill; do NOT grow
// the wave tile under a launch_bounds occupancy clamp (round-4 spill regression).
__global__ __launch_bounds__(256) void kgemm3p(
    const unsigned short* __restrict__ Ah, const unsigned short* __restrict__ Al,
    const unsigned short* __restrict__ Bh, const unsigned short* __restrict__ Bl,
    const float* __restrict__ bias, float* __restrict__ C, int N, int K, int kLen,
    float* __restrict__ bnps, float* __restrict__ bnpq, const float* __restrict__ diag) {
  __shared__ unsigned short As[2][4096];  // [hi|lo][128 rows x 32 k]
  __shared__ unsigned short Bs[2][4096];
  __shared__ float sred[2][2][128];
  int tid = threadIdx.x;
  int lane = tid & 63;
  int wave = tid >> 6;
  int wm = wave >> 1, wn = wave & 1;
  int rowBase = blockIdx.x * 128;
  int colBase = blockIdx.y * 128;
  int kOff = blockIdx.z * kLen;
  C += (size_t)blockIdx.z * gridDim.x * 128 * N;  // split-K partial stripe

  f32x4 acc[4][4];
#pragma unroll
  for (int i = 0; i < 4; i++)
#pragma unroll
    for (int j = 0; j < 4; j++) acc[i][j] = (f32x4){0.f, 0.f, 0.f, 0.f};

  int r4 = tid >> 2;       // 0..63
  int kc = (tid & 3) * 8;  // 0,8,16,24
  int lr = lane & 15;
  int lk = (lane >> 4) * 8;

  const unsigned short* Ah0 = Ah + (size_t)(rowBase + r4) * K + kOff + kc;
  const unsigned short* Al0 = Al + (size_t)(rowBase + r4) * K + kOff + kc;
  const unsigned short* Bh0 = Bh + (size_t)(colBase + r4) * K + kOff + kc;
  const unsigned short* Bl0 = Bl + (size_t)(colBase + r4) * K + kOff + kc;
  size_t rstep = (size_t)64 * K;
  char* AsD = (char*)As + tid * 16;
  char* BsD = (char*)Bs + tid * 16;

  // prologue: stage tile 0
  gll16(Ah0, AsD);        gll16(Ah0 + rstep, AsD + 4096);
  gll16(Al0, AsD + 8192); gll16(Al0 + rstep, AsD + 12288);
  gll16(Bh0, BsD);        gll16(Bh0 + rstep, BsD + 4096);
  gll16(Bl0, BsD + 8192); gll16(Bl0 + rstep, BsD + 12288);
  __syncthreads();  // compiler drains vmcnt before barrier

  int nk = kLen >> 5;
  for (int kt = 0; kt < nk; ++kt) {
    // 1) LDS -> registers (all fragments)
    bf16x8 ah[4], al[4], bh[4], bl[4];
#pragma unroll
    for (int mi = 0; mi < 4; mi++) {
      ah[mi] = *(const bf16x8*)&As[0][(wm * 64 + mi * 16 + lr) * 32 + lk];
      al[mi] = *(const bf16x8*)&As[1][(wm * 64 + mi * 16 + lr) * 32 + lk];
      bh[mi] = *(const bf16x8*)&Bs[0][(wn * 64 + mi * 16 + lr) * 32 + lk];
      bl[mi] = *(const bf16x8*)&Bs[1][(wn * 64 + mi * 16 + lr) * 32 + lk];
    }
    __syncthreads();  // all waves done reading LDS (lgkm drained)

    // 2) issue next tile's staging NOW — latency hides under the MFMAs below
    if (kt + 1 < nk) {
      int k0 = (kt + 1) << 5;
      gll16(Ah0 + k0, AsD);        gll16(Ah0 + k0 + rstep, AsD + 4096);
      gll16(Al0 + k0, AsD + 8192); gll16(Al0 + k0 + rstep, AsD + 12288);
      gll16(Bh0 + k0, BsD);        gll16(Bh0 + k0 + rstep, BsD + 4096);
      gll16(Bl0 + k0, BsD + 8192); gll16(Bl0 + k0 + rstep, BsD + 12288);
    }

    // 3) 48 MFMAs on registers, overlapping the in-flight loads
#pragma unroll
    for (int mi = 0; mi < 4; mi++)
#pragma unroll
      for (int ni = 0; ni < 4; ni++) {
        acc[mi][ni] = __builtin_amdgcn_mfma_f32_16x16x32_bf16(ah[mi], bh[ni], acc[mi][ni], 0, 0, 0);
        acc[mi][ni] = __builtin_amdgcn_mfma_f32_16x16x32_bf16(ah[mi], bl[ni], acc[mi][ni], 0, 0, 0);
        acc[mi][ni] = __builtin_amdgcn_mfma_f32_16x16x32_bf16(al[mi], bh[ni], acc[mi][ni], 0, 0, 0);
      }
    __syncthreads();  // staging complete (vmcnt drained) before next frag reads
  }

  int lg = lane >> 4;
  if (diag) {
    // rate-mode epilogue: out = clip(|acc+bias| * diag[col], 1e-10, 1e7)
#pragma unroll
    for (int mi = 0; mi < 4; mi++)
#pragma unroll
      for (int ni = 0; ni < 4; ni++) {
        int col = colBase + wn * 64 + ni * 16 + lr;
        float bv = bias ? bias[col] : 0.0f;
        float dg = diag[col];
#pragma unroll
        for (int j = 0; j < 4; j++) {
          int row = rowBase + wm * 64 + mi * 16 + lg * 4 + j;
          float r = fabsf(acc[mi][ni][j] + bv) * dg;
          C[(size_t)row * N + col] = fminf(fmaxf(r, 1e-10f), 1e7f);
        }
      }
  } else {
    float s[4] = {0.f, 0.f, 0.f, 0.f}, q[4] = {0.f, 0.f, 0.f, 0.f};
#pragma unroll
    for (int mi = 0; mi < 4; mi++)
#pragma unroll
      for (int ni = 0; ni < 4; ni++) {
        int col = colBase + wn * 64 + ni * 16 + lr;
        float bv = bias ? bias[col] : 0.0f;
#pragma unroll
        for (int j = 0; j < 4; j++) {
          int row = rowBase + wm * 64 + mi * 16 + lg * 4 + j;
          float v = acc[mi][ni][j] + bv;
          C[(size_t)row * N + col] = v;
          s[ni] += v;
          q[ni] += v * v;
        }
      }
    if (bnps) {
      // reduce the 8 threads (lg x wm) covering each column; deterministic
#pragma unroll
      for (int ni = 0; ni < 4; ni++) {
        s[ni] += __shfl_xor(s[ni], 16); s[ni] += __shfl_xor(s[ni], 32);
        q[ni] += __shfl_xor(q[ni], 16); q[ni] += __shfl_xor(q[ni], 32);
      }
      if (lg == 0) {
#pragma unroll
        for (int ni = 0; ni < 4; ni++) {
          sred[wm][0][wn * 64 + ni * 16 + lr] = s[ni];
          sred[wm][1][wn * 64 + ni * 16 + lr] = q[ni];
        }
      }
      __syncthreads();
      if (tid < 128) {
        bnps[(size_t)blockIdx.x * N + colBase + tid] = sred[0][0][tid] + sred[1][0][tid];
        bnpq[(size_t)blockIdx.x * N + colBase + tid] = sred[0][1][tid] + sred[1][1][tid];
      }
    }
  }
}

// ---------------- single-pass bf16 GEMM (reconstruction), register-pipelined ----------------
__global__ __launch_bounds__(256) void kgemm(
    const unsigned short* __restrict__ A, const unsigned short* __restrict__ BT,
    float* __restrict__ C, int N, int K) {
  __shared__ unsigned short As[4096];
  __shared__ unsigned short Bs[4096];
  int tid = threadIdx.x;
  int lane = tid & 63;
  int wave = tid >> 6;
  int wm = wave >> 1, wn = wave & 1;
  int rowBase = blockIdx.x * 128;
  int colBase = blockIdx.y * 128;

  f32x4 acc[4][4];
#pragma unroll
  for (int i = 0; i < 4; i++)
#pragma unroll
    for (int j = 0; j < 4; j++) acc[i][j] = (f32x4){0.f, 0.f, 0.f, 0.f};

  int r4 = tid >> 2;
  int kc = (tid & 3) * 8;
  int lr = lane & 15;
  int lk = (lane >> 4) * 8;

  const unsigned short* A0 = A + (size_t)(rowBase + r4) * K + kc;
  const unsigned short* B0 = BT + (size_t)(colBase + r4) * K + kc;
  size_t rstep = (size_t)64 * K;
  char* AsD = (char*)As + tid * 16;
  char* BsD = (char*)Bs + tid * 16;

  gll16(A0, AsD); gll16(A0 + rstep, AsD + 4096);
  gll16(B0, BsD); gll16(B0 + rstep, BsD + 4096);
  __syncthreads();

  int nk = K >> 5;
  for (int kt = 0; kt < nk; ++kt) {
    bf16x8 af[4], bfr[4];
#pragma unroll
    for (int mi = 0; mi < 4; mi++) {
      af[mi] = *(const bf16x8*)&As[(wm * 64 + mi * 16 + lr) * 32 + lk];
      bfr[mi] = *(const bf16x8*)&Bs[(wn * 64 + mi * 16 + lr) * 32 + lk];
    }
    __syncthreads();
    if (kt + 1 < nk) {
      int k0 = (kt + 1) << 5;
      gll16(A0 + k0, AsD); gll16(A0 + k0 + rstep, AsD + 4096);
      gll16(B0 + k0, BsD); gll16(B0 + k0 + rstep, BsD + 4096);
    }
#pragma unroll
    for (int mi = 0; mi < 4; mi++)
#pragma unroll
      for (int ni = 0; ni < 4; ni++)
        acc[mi][ni] = __builtin_amdgcn_mfma_f32_16x16x32_bf16(af[mi], bfr[ni], acc[mi][ni], 0, 0, 0);
    __syncthreads();
  }

  int lg = lane >> 4;
#pragma unroll
  for (int mi = 0; mi < 4; mi++)
#pragma unroll
    for (int ni = 0; ni < 4; ni++) {
      int col = colBase + wn * 64 + ni * 16 + lr;
#pragma unroll
      for (int j = 0; j < 4; j++) {
        int row = rowBase + wm * 64 + mi * 16 + lg * 4 + j;
        C[(size_t)row * N + col] = acc[mi][ni][j];
      }
    }
}

// ---- split-K combine + bias + BN column partials (one 128-row stripe per block.y) ----
__global__ void kcombine_bn(const float* __restrict__ Cp, const float* __restrict__ bias,
                            float* __restrict__ y, float* __restrict__ ps, float* __restrict__ pq,
                            int N, int splits, int splitStride) {
  int c = blockIdx.x * 128 + threadIdx.x;
  int r0 = blockIdx.y * 128;
  float bv = bias[c];
  float s = 0.f, q = 0.f;
  for (int r = r0; r < r0 + 128; ++r) {
    float v = bv;
    for (int z = 0; z < splits; ++z) v += Cp[(size_t)z * splitStride + (size_t)r * N + c];
    y[(size_t)r * N + c] = v;
    s += v;
    q += v * v;
  }
  ps[blockIdx.y * N + c] = s;
  pq[blockIdx.y * N + c] = q;
}

__global__ void kbn_final(const float* __restrict__ ps, const float* __restrict__ pq,
                          const float* __restrict__ g, const float* __restrict__ b,
                          float* __restrict__ scale, float* __restrict__ shift, int N,
                          int stripes) {
  int c = blockIdx.x * blockDim.x + threadIdx.x;
  if (c >= N) return;
  float s = 0.f, q = 0.f;
  for (int i = 0; i < stripes; ++i) {
    s += ps[i * N + c];
    q += pq[i * N + c];
  }
  float m = s * (1.0f / 4096.0f);
  float var = q * (1.0f / 4096.0f) - m * m;
  float sc = g[c] * rsqrtf(var + 1e-5f);
  scale[c] = sc;
  shift[c] = b[c] - m * sc;
}

// BN apply + ReLU + split-bf16 output, 4 elems/thread
__global__ void kbn_apply_split4(const float4* __restrict__ y, const float* __restrict__ scale,
                                 const float* __restrict__ shift, ushort4* __restrict__ hhi,
                                 ushort4* __restrict__ hlo, int mask) {
  int i = blockIdx.x * blockDim.x + threadIdx.x;
  int c0 = (i << 2) & mask;
  float4 v = y[i];
  ushort4 h, l;
  float t;
  t = v.x * scale[c0] + shift[c0];         t = t > 0.f ? t : 0.f; h.x = f2bf(t); l.x = f2bf(t - bf2f(h.x));
  t = v.y * scale[c0 + 1] + shift[c0 + 1]; t = t > 0.f ? t : 0.f; h.y = f2bf(t); l.y = f2bf(t - bf2f(h.y));
  t = v.z * scale[c0 + 2] + shift[c0 + 2]; t = t > 0.f ? t : 0.f; h.z = f2bf(t); l.z = f2bf(t - bf2f(h.z));
  t = v.w * scale[c0 + 3] + shift[c0 + 3]; t = t > 0.f ? t : 0.f; h.w = f2bf(t); l.w = f2bf(t - bf2f(h.w));
  hhi[i] = h;
  hlo[i] = l;
}

// ---------------- decoder normalization ----------------
__global__ void kdec(const float* __restrict__ dec_w, float* __restrict__ decode,
                     unsigned short* __restrict__ decT, float* __restrict__ diag) {
  int h = blockIdx.x, tx = threadIdx.x;
  __shared__ float red[256];
  float s = 0.f;
  for (int i = tx; i < 1024; i += 256) s += dec_w[h * 1024 + i];
  red[tx] = s;
  __syncthreads();
  for (int k = 128; k > 0; k >>= 1) {
    if (tx < k) red[tx] += red[tx + k];
    __syncthreads();
  }
  float d = fabsf(red[0]);
  if (tx == 0) diag[h] = d;
  float inv = 1.0f / d;
  for (int i = tx; i < 1024; i += 256) {
    float v = fabsf(dec_w[h * 1024 + i]) * inv;
    decode[h * 1024 + i] = v;
    decT[i * 128 + h] = f2bf(v);
  }
}

// ---------------- Poisson rsample with early exit ----------------
__global__ __launch_bounds__(256) void kpoisson(const float* __restrict__ u,
                                                const float* __restrict__ rate,
                                                float* __restrict__ samples,
                                                unsigned short* __restrict__ sb) {
  int tid = blockIdx.x * 256 + threadIdx.x;
  int h = tid & 127;
  int b = tid >> 7;
  float r = rate[tid];
  float inv = 1.0f / r;
  const float* up = u + (size_t)b * (512 * 128) + h;
  float t = 0.f, s = 0.f;
  for (int nt = 0; nt < 512; ++nt) {
    float uv = up[(size_t)nt * 128];
    t += (-__logf(uv)) * inv;
    float z = (t - 1.0f) * 10.0f;
    s += __frcp_rn(1.0f + __expf(z));
    if (t > 4.0f) break;
  }
  samples[tid] = s;
  sb[tid] = f2bf(s);
}

extern "C" void kernel_launch(void* const* d_in, const int* in_sizes, int n_in,
                              void* d_out, int out_size, void* d_ws, size_t ws_size,
                              hipStream_t stream) {
  const float* x = (const float*)d_in[0];
  const float* u = (const float*)d_in[1];
  const float* w1 = (const float*)d_in[2];
  const float* b1 = (const float*)d_in[3];
  const float* g1 = (const float*)d_in[4];
  const float* bb1 = (const float*)d_in[5];
  const float* w2 = (const float*)d_in[6];
  const float* b2 = (const float*)d_in[7];
  const float* g2 = (const float*)d_in[8];
  const float* bb2 = (const float*)d_in[9];
  const float* w3 = (const float*)d_in[10];
  const float* b3 = (const float*)d_in[11];
  const float* g3 = (const float*)d_in[12];
  const float* bb3 = (const float*)d_in[13];
  const float* w4 = (const float*)d_in[14];
  const float* b4 = (const float*)d_in[15];
  const float* dw = (const float*)d_in[16];

  float* out = (float*)d_out;
  float* out_xrec = out;            // [4096][1024]
  float* out_samp = out + 4194304;  // [4096][128]
  float* out_rate = out + 4718592;  // [4096][128]
  float* out_dec = out + 5242880;   // [128][1024]

  char* w = (char*)d_ws;
  unsigned short* xhi = (unsigned short*)w;  w += 8388608;   // [4096][1024]
  unsigned short* xlo = (unsigned short*)w;  w += 8388608;
  unsigned short* w1th = (unsigned short*)w; w += 4194304;   // [2048][1024]
  unsigned short* w1tl = (unsigned short*)w; w += 4194304;
  unsigned short* w2th = (unsigned short*)w; w += 4194304;   // [1024][2048]
  unsigned short* w2tl = (unsigned short*)w; w += 4194304;
  unsigned short* w3th = (unsigned short*)w; w += 262144;    // [128][1024]
  unsigned short* w3tl = (unsigned short*)w; w += 262144;
  unsigned short* w4th = (unsigned short*)w; w += 32768;     // [128][128]
  unsigned short* w4tl = (unsigned short*)w; w += 32768;
  float* y = (float*)w;             w += 33554432;           // y1 [4096][2048], reused as y2
  unsigned short* h1h = (unsigned short*)w; w += 16777216;   // [4096][2048]
  unsigned short* h1l = (unsigned short*)w; w += 16777216;
  unsigned short* h2h = (unsigned short*)w; w += 8388608;    // [4096][1024]
  unsigned short* h2l = (unsigned short*)w; w += 8388608;
  unsigned short* h3h = (unsigned short*)w; w += 1048576;    // [4096][128]
  unsigned short* h3l = (unsigned short*)w; w += 1048576;
  float* y3 = (float*)w;            w += 2097152;            // [4096][128]
  float* Cp = (float*)w;            w += 33554432;           // split-K partials (<=32MB)
  unsigned short* sb = (unsigned short*)w; w += 1048576;     // samples bf16
  unsigned short* dct = (unsigned short*)w; w += 262144;     // decode^T bf16 [1024][128]
  float* diag = (float*)w;          w += 1024;
  float* ps = (float*)w;            w += 262144;             // [<=32][N<=2048]
  float* pq = (float*)w;            w += 262144;
  float* scale = (float*)w;         w += 8192;
  float* shift = (float*)w;         w += 8192;

  // --- prep ---
  kconvert_split4<<<4096, 256, 0, stream>>>((const float4*)x, (ushort4*)xhi, (ushort4*)xlo, 1048576);
  ktranspose_split<<<dim3(64, 32), 256, 0, stream>>>(w1, w1th, w1tl, 1024, 2048);
  ktranspose_split<<<dim3(32, 64), 256, 0, stream>>>(w2, w2th, w2tl, 2048, 1024);
  ktranspose_split<<<dim3(4, 32), 256, 0, stream>>>(w3, w3th, w3tl, 1024, 128);
  ktranspose_split<<<dim3(4, 4), 256, 0, stream>>>(w4, w4th, w4tl, 128, 128);
  kdec<<<128, 256, 0, stream>>>(dw, out_dec, dct, diag);

  // --- encoder layer 1 (BN partials fused into GEMM epilogue) ---
  kgemm3p<<<dim3(32, 16), 256, 0, stream>>>(xhi, xlo, w1th, w1tl, b1, y, 2048, 1024, 1024,
                                            ps, pq, nullptr);
  kbn_final<<<8, 256, 0, stream>>>(ps, pq, g1, bb1, scale, shift, 2048, 32);
  kbn_apply_split4<<<8192, 256, 0, stream>>>((const float4*)y, scale, shift, (ushort4*)h1h,
                                             (ushort4*)h1l, 2047);

  // --- encoder layer 2: split-K=2 (512 blocks -> 2 waves/SIMD), combine+BN fused ---
  kgemm3p<<<dim3(32, 8, 2), 256, 0, stream>>>(h1h, h1l, w2th, w2tl, nullptr, Cp, 1024, 2048,
                                              1024, nullptr, nullptr, nullptr);
  kcombine_bn<<<dim3(8, 32), 128, 0, stream>>>(Cp, b2, y, ps, pq, 1024, 2, 4194304);
  kbn_final<<<4, 256, 0, stream>>>(ps, pq, g2, bb2, scale, shift, 1024, 32);
  kbn_apply_split4<<<4096, 256, 0, stream>>>((const float4*)y, scale, shift, (ushort4*)h2h,
                                             (ushort4*)h2l, 1023);

  // --- encoder layer 3: split-K=8 (256 blocks), combine+BN fused ---
  kgemm3p<<<dim3(32, 1, 8), 256, 0, stream>>>(h2h, h2l, w3th, w3tl, nullptr, Cp, 128, 1024, 128,
                                              nullptr, nullptr, nullptr);
  kcombine_bn<<<dim3(1, 32), 128, 0, stream>>>(Cp, b3, y3, ps, pq, 128, 8, 524288);
  kbn_final<<<1, 128, 0, stream>>>(ps, pq, g3, bb3, scale, shift, 128, 32);
  kbn_apply_split4<<<512, 256, 0, stream>>>((const float4*)y3, scale, shift, (ushort4*)h3h,
                                            (ushort4*)h3l, 127);

  // --- lambda head + rate (fused epilogue) ---
  kgemm3p<<<dim3(32, 1), 256, 0, stream>>>(h3h, h3l, w4th, w4tl, b4, out_rate, 128, 128, 128,
                                           nullptr, nullptr, diag);

  // --- Poisson rsample ---
  kpoisson<<<2048, 256, 0, stream>>>(u, out_rate, out_samp, sb);

  // --- reconstruction ---
  kgemm<<<dim3(32, 8), 256, 0, stream>>>(sb, dct, out_xrec, 1024, 128);
}

// Round 6
// 275.439 us; speedup vs baseline: 2.1770x; 2.0264x over previous
//
#include <hip/hip_runtime.h>
#include <stdint.h>

// B=4096, IN=1024, L0=2048, L1=1024, H=128, NT=512, T=0.1, EPS=1e-5
// EXACT revert to the round-3 source (274.65 us, passed) — A/B to isolate the
// rounds-4/5 regression (GEMM2/3 split-K + kcombine_bn) from environment drift.

typedef __attribute__((ext_vector_type(8))) __bf16 bf16x8;
typedef __attribute__((ext_vector_type(4))) float f32x4;
typedef unsigned short ushort_t;

__device__ __forceinline__ unsigned short f2bf(float f) {
  unsigned int u = __float_as_uint(f);
  unsigned int r = (u + 0x7fffu + ((u >> 16) & 1u)) >> 16;  // RNE
  return (unsigned short)r;
}
__device__ __forceinline__ float bf2f(unsigned short h) {
  return __uint_as_float(((unsigned int)h) << 16);
}

__device__ __forceinline__ void gll16(const void* g, void* l) {
  __builtin_amdgcn_global_load_lds(
      (const __attribute__((address_space(1))) unsigned int*)g,
      (__attribute__((address_space(3))) unsigned int*)l, 16, 0, 0);
}

// ---------------- f32 -> split bf16 (hi, lo), 4 elems/thread ----------------
__global__ void kconvert_split4(const float4* __restrict__ in, ushort4* __restrict__ hi,
                                ushort4* __restrict__ lo, int n4) {
  int i = blockIdx.x * blockDim.x + threadIdx.x;
  if (i < n4) {
    float4 v = in[i];
    ushort4 h, l;
    h.x = f2bf(v.x); l.x = f2bf(v.x - bf2f(h.x));
    h.y = f2bf(v.y); l.y = f2bf(v.y - bf2f(h.y));
    h.z = f2bf(v.z); l.z = f2bf(v.z - bf2f(h.z));
    h.w = f2bf(v.w); l.w = f2bf(v.w - bf2f(h.w));
    hi[i] = h; lo[i] = l;
  }
}

// ---------------- transpose + split convert: in[R][C] f32 -> out[C][R] split bf16 ----------------
__global__ void ktranspose_split(const float* __restrict__ in, unsigned short* __restrict__ ohi,
                                 unsigned short* __restrict__ olo, int R, int C) {
  __shared__ unsigned short th[32][33];
  __shared__ unsigned short tl[32][33];
  int c0 = blockIdx.x * 32, r0 = blockIdx.y * 32;
  int tx = threadIdx.x & 31, ty = threadIdx.x >> 5;  // 32 x 8
#pragma unroll
  for (int i = 0; i < 32; i += 8) {
    float v = in[(size_t)(r0 + ty + i) * C + c0 + tx];
    unsigned short h = f2bf(v);
    th[ty + i][tx] = h;
    tl[ty + i][tx] = f2bf(v - bf2f(h));
  }
  __syncthreads();
#pragma unroll
  for (int i = 0; i < 32; i += 8) {
    ohi[(size_t)(c0 + ty + i) * R + r0 + tx] = th[tx][ty + i];
    olo[(size_t)(c0 + ty + i) * R + r0 + tx] = tl[tx][ty + i];
  }
}

// ---------------- split-bf16 3-pass MFMA GEMM, register-pipelined ----------------
// C[M][N] = (Ah+Al)[M][K] @ (Bh+Bl)[N][K]^T (+bias), dropping Al*Bl.
// grid = (M/128, N/128, splits). kOff = blockIdx.z*kLen.
// Epilogues: diag!=null -> rate mode (clip(|v|*diag[col])); bnps!=null -> BN col partials.
__global__ __launch_bounds__(256) void kgemm3p(
    const unsigned short* __restrict__ Ah, const unsigned short* __restrict__ Al,
    const unsigned short* __restrict__ Bh, const unsigned short* __restrict__ Bl,
    const float* __restrict__ bias, float* __restrict__ C, int N, int K, int kLen,
    float* __restrict__ bnps, float* __restrict__ bnpq, const float* __restrict__ diag) {
  __shared__ unsigned short As[2][4096];  // [hi|lo][128 rows x 32 k]
  __shared__ unsigned short Bs[2][4096];
  __shared__ float sred[2][2][128];
  int tid = threadIdx.x;
  int lane = tid & 63;
  int wave = tid >> 6;
  int wm = wave >> 1, wn = wave & 1;
  int rowBase = blockIdx.x * 128;
  int colBase = blockIdx.y * 128;
  int kOff = blockIdx.z * kLen;
  C += (size_t)blockIdx.z * gridDim.x * 128 * N;  // split-K partial stripe

  f32x4 acc[4][4];
#pragma unroll
  for (int i = 0; i < 4; i++)
#pragma unroll
    for (int j = 0; j < 4; j++) acc[i][j] = (f32x4){0.f, 0.f, 0.f, 0.f};

  int r4 = tid >> 2;       // 0..63
  int kc = (tid & 3) * 8;  // 0,8,16,24
  int lr = lane & 15;
  int lk = (lane >> 4) * 8;

  const unsigned short* Ah0 = Ah + (size_t)(rowBase + r4) * K + kOff + kc;
  const unsigned short* Al0 = Al + (size_t)(rowBase + r4) * K + kOff + kc;
  const unsigned short* Bh0 = Bh + (size_t)(colBase + r4) * K + kOff + kc;
  const unsigned short* Bl0 = Bl + (size_t)(colBase + r4) * K + kOff + kc;
  size_t rstep = (size_t)64 * K;
  char* AsD = (char*)As + tid * 16;
  char* BsD = (char*)Bs + tid * 16;

  // prologue: stage tile 0
  gll16(Ah0, AsD);        gll16(Ah0 + rstep, AsD + 4096);
  gll16(Al0, AsD + 8192); gll16(Al0 + rstep, AsD + 12288);
  gll16(Bh0, BsD);        gll16(Bh0 + rstep, BsD + 4096);
  gll16(Bl0, BsD + 8192); gll16(Bl0 + rstep, BsD + 12288);
  __syncthreads();  // compiler drains vmcnt before barrier

  int nk = kLen >> 5;
  for (int kt = 0; kt < nk; ++kt) {
    // 1) LDS -> registers (all fragments)
    bf16x8 ah[4], al[4], bh[4], bl[4];
#pragma unroll
    for (int mi = 0; mi < 4; mi++) {
      ah[mi] = *(const bf16x8*)&As[0][(wm * 64 + mi * 16 + lr) * 32 + lk];
      al[mi] = *(const bf16x8*)&As[1][(wm * 64 + mi * 16 + lr) * 32 + lk];
      bh[mi] = *(const bf16x8*)&Bs[0][(wn * 64 + mi * 16 + lr) * 32 + lk];
      bl[mi] = *(const bf16x8*)&Bs[1][(wn * 64 + mi * 16 + lr) * 32 + lk];
    }
    __syncthreads();  // all waves done reading LDS (lgkm drained)

    // 2) issue next tile's staging NOW — latency hides under the MFMAs below
    if (kt + 1 < nk) {
      int k0 = (kt + 1) << 5;
      gll16(Ah0 + k0, AsD);        gll16(Ah0 + k0 + rstep, AsD + 4096);
      gll16(Al0 + k0, AsD + 8192); gll16(Al0 + k0 + rstep, AsD + 12288);
      gll16(Bh0 + k0, BsD);        gll16(Bh0 + k0 + rstep, BsD + 4096);
      gll16(Bl0 + k0, BsD + 8192); gll16(Bl0 + k0 + rstep, BsD + 12288);
    }

    // 3) 48 MFMAs on registers, overlapping the in-flight loads
#pragma unroll
    for (int mi = 0; mi < 4; mi++)
#pragma unroll
      for (int ni = 0; ni < 4; ni++) {
        acc[mi][ni] = __builtin_amdgcn_mfma_f32_16x16x32_bf16(ah[mi], bh[ni], acc[mi][ni], 0, 0, 0);
        acc[mi][ni] = __builtin_amdgcn_mfma_f32_16x16x32_bf16(ah[mi], bl[ni], acc[mi][ni], 0, 0, 0);
        acc[mi][ni] = __builtin_amdgcn_mfma_f32_16x16x32_bf16(al[mi], bh[ni], acc[mi][ni], 0, 0, 0);
      }
    __syncthreads();  // staging complete (vmcnt drained) before next frag reads
  }

  int lg = lane >> 4;
  if (diag) {
    // rate-mode epilogue: out = clip(|acc+bias| * diag[col], 1e-10, 1e7)
#pragma unroll
    for (int mi = 0; mi < 4; mi++)
#pragma unroll
      for (int ni = 0; ni < 4; ni++) {
        int col = colBase + wn * 64 + ni * 16 + lr;
        float bv = bias ? bias[col] : 0.0f;
        float dg = diag[col];
#pragma unroll
        for (int j = 0; j < 4; j++) {
          int row = rowBase + wm * 64 + mi * 16 + lg * 4 + j;
          float r = fabsf(acc[mi][ni][j] + bv) * dg;
          C[(size_t)row * N + col] = fminf(fmaxf(r, 1e-10f), 1e7f);
        }
      }
  } else {
    float s[4] = {0.f, 0.f, 0.f, 0.f}, q[4] = {0.f, 0.f, 0.f, 0.f};
#pragma unroll
    for (int mi = 0; mi < 4; mi++)
#pragma unroll
      for (int ni = 0; ni < 4; ni++) {
        int col = colBase + wn * 64 + ni * 16 + lr;
        float bv = bias ? bias[col] : 0.0f;
#pragma unroll
        for (int j = 0; j < 4; j++) {
          int row = rowBase + wm * 64 + mi * 16 + lg * 4 + j;
          float v = acc[mi][ni][j] + bv;
          C[(size_t)row * N + col] = v;
          s[ni] += v;
          q[ni] += v * v;
        }
      }
    if (bnps) {
      // reduce the 8 threads (lg x wm) covering each column; deterministic
#pragma unroll
      for (int ni = 0; ni < 4; ni++) {
        s[ni] += __shfl_xor(s[ni], 16); s[ni] += __shfl_xor(s[ni], 32);
        q[ni] += __shfl_xor(q[ni], 16); q[ni] += __shfl_xor(q[ni], 32);
      }
      if (lg == 0) {
#pragma unroll
        for (int ni = 0; ni < 4; ni++) {
          sred[wm][0][wn * 64 + ni * 16 + lr] = s[ni];
          sred[wm][1][wn * 64 + ni * 16 + lr] = q[ni];
        }
      }
      __syncthreads();
      if (tid < 128) {
        bnps[(size_t)blockIdx.x * N + colBase + tid] = sred[0][0][tid] + sred[1][0][tid];
        bnpq[(size_t)blockIdx.x * N + colBase + tid] = sred[0][1][tid] + sred[1][1][tid];
      }
    }
  }
}

// ---------------- single-pass bf16 GEMM (reconstruction), register-pipelined ----------------
__global__ __launch_bounds__(256) void kgemm(
    const unsigned short* __restrict__ A, const unsigned short* __restrict__ BT,
    float* __restrict__ C, int N, int K) {
  __shared__ unsigned short As[4096];
  __shared__ unsigned short Bs[4096];
  int tid = threadIdx.x;
  int lane = tid & 63;
  int wave = tid >> 6;
  int wm = wave >> 1, wn = wave & 1;
  int rowBase = blockIdx.x * 128;
  int colBase = blockIdx.y * 128;

  f32x4 acc[4][4];
#pragma unroll
  for (int i = 0; i < 4; i++)
#pragma unroll
    for (int j = 0; j < 4; j++) acc[i][j] = (f32x4){0.f, 0.f, 0.f, 0.f};

  int r4 = tid >> 2;
  int kc = (tid & 3) * 8;
  int lr = lane & 15;
  int lk = (lane >> 4) * 8;

  const unsigned short* A0 = A + (size_t)(rowBase + r4) * K + kc;
  const unsigned short* B0 = BT + (size_t)(colBase + r4) * K + kc;
  size_t rstep = (size_t)64 * K;
  char* AsD = (char*)As + tid * 16;
  char* BsD = (char*)Bs + tid * 16;

  gll16(A0, AsD); gll16(A0 + rstep, AsD + 4096);
  gll16(B0, BsD); gll16(B0 + rstep, BsD + 4096);
  __syncthreads();

  int nk = K >> 5;
  for (int kt = 0; kt < nk; ++kt) {
    bf16x8 af[4], bfr[4];
#pragma unroll
    for (int mi = 0; mi < 4; mi++) {
      af[mi] = *(const bf16x8*)&As[(wm * 64 + mi * 16 + lr) * 32 + lk];
      bfr[mi] = *(const bf16x8*)&Bs[(wn * 64 + mi * 16 + lr) * 32 + lk];
    }
    __syncthreads();
    if (kt + 1 < nk) {
      int k0 = (kt + 1) << 5;
      gll16(A0 + k0, AsD); gll16(A0 + k0 + rstep, AsD + 4096);
      gll16(B0 + k0, BsD); gll16(B0 + k0 + rstep, BsD + 4096);
    }
#pragma unroll
    for (int mi = 0; mi < 4; mi++)
#pragma unroll
      for (int ni = 0; ni < 4; ni++)
        acc[mi][ni] = __builtin_amdgcn_mfma_f32_16x16x32_bf16(af[mi], bfr[ni], acc[mi][ni], 0, 0, 0);
    __syncthreads();
  }

  int lg = lane >> 4;
#pragma unroll
  for (int mi = 0; mi < 4; mi++)
#pragma unroll
    for (int ni = 0; ni < 4; ni++) {
      int col = colBase + wn * 64 + ni * 16 + lr;
#pragma unroll
      for (int j = 0; j < 4; j++) {
        int row = rowBase + wm * 64 + mi * 16 + lg * 4 + j;
        C[(size_t)row * N + col] = acc[mi][ni][j];
      }
    }
}

// ---------------- BN partials for L3 (y3 is tiny) ----------------
__global__ void kbn_partial(const float* __restrict__ y, float* __restrict__ ps,
                            float* __restrict__ pq, int N) {
  int c = blockIdx.x * blockDim.x + threadIdx.x;
  int r0 = blockIdx.y * 128;
  float s = 0.f, q = 0.f;
  for (int r = r0; r < r0 + 128; ++r) {
    float v = y[(size_t)r * N + c];
    s += v;
    q += v * v;
  }
  ps[blockIdx.y * N + c] = s;
  pq[blockIdx.y * N + c] = q;
}

__global__ void kbn_final(const float* __restrict__ ps, const float* __restrict__ pq,
                          const float* __restrict__ g, const float* __restrict__ b,
                          float* __restrict__ scale, float* __restrict__ shift, int N,
                          int stripes) {
  int c = blockIdx.x * blockDim.x + threadIdx.x;
  if (c >= N) return;
  float s = 0.f, q = 0.f;
  for (int i = 0; i < stripes; ++i) {
    s += ps[i * N + c];
    q += pq[i * N + c];
  }
  float m = s * (1.0f / 4096.0f);
  float var = q * (1.0f / 4096.0f) - m * m;
  float sc = g[c] * rsqrtf(var + 1e-5f);
  scale[c] = sc;
  shift[c] = b[c] - m * sc;
}

// BN apply + ReLU + split-bf16 output, 4 elems/thread
__global__ void kbn_apply_split4(const float4* __restrict__ y, const float* __restrict__ scale,
                                 const float* __restrict__ shift, ushort4* __restrict__ hhi,
                                 ushort4* __restrict__ hlo, int mask) {
  int i = blockIdx.x * blockDim.x + threadIdx.x;
  int c0 = (i << 2) & mask;
  float4 v = y[i];
  ushort4 h, l;
  float t;
  t = v.x * scale[c0] + shift[c0];         t = t > 0.f ? t : 0.f; h.x = f2bf(t); l.x = f2bf(t - bf2f(h.x));
  t = v.y * scale[c0 + 1] + shift[c0 + 1]; t = t > 0.f ? t : 0.f; h.y = f2bf(t); l.y = f2bf(t - bf2f(h.y));
  t = v.z * scale[c0 + 2] + shift[c0 + 2]; t = t > 0.f ? t : 0.f; h.z = f2bf(t); l.z = f2bf(t - bf2f(h.z));
  t = v.w * scale[c0 + 3] + shift[c0 + 3]; t = t > 0.f ? t : 0.f; h.w = f2bf(t); l.w = f2bf(t - bf2f(h.w));
  hhi[i] = h;
  hlo[i] = l;
}

// ---------------- split-K combine for L3: y3 = sum_z Cp[z] + bias ----------------
__global__ void kcombine(const float4* __restrict__ Cp, const float* __restrict__ bias,
                         float4* __restrict__ y, int n4, int splitStride4, int splits, int mask) {
  int i = blockIdx.x * blockDim.x + threadIdx.x;
  if (i >= n4) return;
  int c0 = (i << 2) & mask;
  float4 a = Cp[i];
  for (int z = 1; z < splits; ++z) {
    float4 b = Cp[(size_t)z * splitStride4 + i];
    a.x += b.x; a.y += b.y; a.z += b.z; a.w += b.w;
  }
  a.x += bias[c0]; a.y += bias[c0 + 1]; a.z += bias[c0 + 2]; a.w += bias[c0 + 3];
  y[i] = a;
}

// ---------------- decoder normalization ----------------
__global__ void kdec(const float* __restrict__ dec_w, float* __restrict__ decode,
                     unsigned short* __restrict__ decT, float* __restrict__ diag) {
  int h = blockIdx.x, tx = threadIdx.x;
  __shared__ float red[256];
  float s = 0.f;
  for (int i = tx; i < 1024; i += 256) s += dec_w[h * 1024 + i];
  red[tx] = s;
  __syncthreads();
  for (int k = 128; k > 0; k >>= 1) {
    if (tx < k) red[tx] += red[tx + k];
    __syncthreads();
  }
  float d = fabsf(red[0]);
  if (tx == 0) diag[h] = d;
  float inv = 1.0f / d;
  for (int i = tx; i < 1024; i += 256) {
    float v = fabsf(dec_w[h * 1024 + i]) * inv;
    decode[h * 1024 + i] = v;
    decT[i * 128 + h] = f2bf(v);
  }
}

// ---------------- Poisson rsample with early exit ----------------
__global__ __launch_bounds__(256) void kpoisson(const float* __restrict__ u,
                                                const float* __restrict__ rate,
                                                float* __restrict__ samples,
                                                unsigned short* __restrict__ sb) {
  int tid = blockIdx.x * 256 + threadIdx.x;
  int h = tid & 127;
  int b = tid >> 7;
  float r = rate[tid];
  float inv = 1.0f / r;
  const float* up = u + (size_t)b * (512 * 128) + h;
  float t = 0.f, s = 0.f;
  for (int nt = 0; nt < 512; ++nt) {
    float uv = up[(size_t)nt * 128];
    t += (-__logf(uv)) * inv;
    float z = (t - 1.0f) * 10.0f;
    s += __frcp_rn(1.0f + __expf(z));
    if (t > 4.0f) break;
  }
  samples[tid] = s;
  sb[tid] = f2bf(s);
}

extern "C" void kernel_launch(void* const* d_in, const int* in_sizes, int n_in,
                              void* d_out, int out_size, void* d_ws, size_t ws_size,
                              hipStream_t stream) {
  const float* x = (const float*)d_in[0];
  const float* u = (const float*)d_in[1];
  const float* w1 = (const float*)d_in[2];
  const float* b1 = (const float*)d_in[3];
  const float* g1 = (const float*)d_in[4];
  const float* bb1 = (const float*)d_in[5];
  const float* w2 = (const float*)d_in[6];
  const float* b2 = (const float*)d_in[7];
  const float* g2 = (const float*)d_in[8];
  const float* bb2 = (const float*)d_in[9];
  const float* w3 = (const float*)d_in[10];
  const float* b3 = (const float*)d_in[11];
  const float* g3 = (const float*)d_in[12];
  const float* bb3 = (const float*)d_in[13];
  const float* w4 = (const float*)d_in[14];
  const float* b4 = (const float*)d_in[15];
  const float* dw = (const float*)d_in[16];

  float* out = (float*)d_out;
  float* out_xrec = out;            // [4096][1024]
  float* out_samp = out + 4194304;  // [4096][128]
  float* out_rate = out + 4718592;  // [4096][128]
  float* out_dec = out + 5242880;   // [128][1024]

  char* w = (char*)d_ws;
  unsigned short* xhi = (unsigned short*)w;  w += 8388608;   // [4096][1024]
  unsigned short* xlo = (unsigned short*)w;  w += 8388608;
  unsigned short* w1th = (unsigned short*)w; w += 4194304;   // [2048][1024]
  unsigned short* w1tl = (unsigned short*)w; w += 4194304;
  unsigned short* w2th = (unsigned short*)w; w += 4194304;   // [1024][2048]
  unsigned short* w2tl = (unsigned short*)w; w += 4194304;
  unsigned short* w3th = (unsigned short*)w; w += 262144;    // [128][1024]
  unsigned short* w3tl = (unsigned short*)w; w += 262144;
  unsigned short* w4th = (unsigned short*)w; w += 32768;     // [128][128]
  unsigned short* w4tl = (unsigned short*)w; w += 32768;
  float* y = (float*)w;             w += 33554432;           // y1 [4096][2048], reused as y2
  unsigned short* h1h = (unsigned short*)w; w += 16777216;   // [4096][2048]
  unsigned short* h1l = (unsigned short*)w; w += 16777216;
  unsigned short* h2h = (unsigned short*)w; w += 8388608;    // [4096][1024]
  unsigned short* h2l = (unsigned short*)w; w += 8388608;
  unsigned short* h3h = (unsigned short*)w; w += 1048576;    // [4096][128]
  unsigned short* h3l = (unsigned short*)w; w += 1048576;
  float* y3 = (float*)w;            w += 2097152;            // [4096][128]
  float* Cp = (float*)w;            w += 8388608;            // split-K partials [4][4096][128]
  unsigned short* sb = (unsigned short*)w; w += 1048576;     // samples bf16
  unsigned short* dct = (unsigned short*)w; w += 262144;     // decode^T bf16 [1024][128]
  float* diag = (float*)w;          w += 1024;
  float* ps = (float*)w;            w += 262144;             // [<=32][N<=2048]
  float* pq = (float*)w;            w += 262144;
  float* scale = (float*)w;         w += 8192;
  float* shift = (float*)w;         w += 8192;

  // --- prep ---
  kconvert_split4<<<4096, 256, 0, stream>>>((const float4*)x, (ushort4*)xhi, (ushort4*)xlo, 1048576);
  ktranspose_split<<<dim3(64, 32), 256, 0, stream>>>(w1, w1th, w1tl, 1024, 2048);
  ktranspose_split<<<dim3(32, 64), 256, 0, stream>>>(w2, w2th, w2tl, 2048, 1024);
  ktranspose_split<<<dim3(4, 32), 256, 0, stream>>>(w3, w3th, w3tl, 1024, 128);
  ktranspose_split<<<dim3(4, 4), 256, 0, stream>>>(w4, w4th, w4tl, 128, 128);
  kdec<<<128, 256, 0, stream>>>(dw, out_dec, dct, diag);

  // --- encoder layer 1 (BN partials fused into GEMM epilogue) ---
  kgemm3p<<<dim3(32, 16), 256, 0, stream>>>(xhi, xlo, w1th, w1tl, b1, y, 2048, 1024, 1024,
                                            ps, pq, nullptr);
  kbn_final<<<8, 256, 0, stream>>>(ps, pq, g1, bb1, scale, shift, 2048, 32);
  kbn_apply_split4<<<8192, 256, 0, stream>>>((const float4*)y, scale, shift, (ushort4*)h1h,
                                             (ushort4*)h1l, 2047);

  // --- encoder layer 2 ---
  kgemm3p<<<dim3(32, 8), 256, 0, stream>>>(h1h, h1l, w2th, w2tl, b2, y, 1024, 2048, 2048,
                                           ps, pq, nullptr);
  kbn_final<<<4, 256, 0, stream>>>(ps, pq, g2, bb2, scale, shift, 1024, 32);
  kbn_apply_split4<<<4096, 256, 0, stream>>>((const float4*)y, scale, shift, (ushort4*)h2h,
                                             (ushort4*)h2l, 1023);

  // --- encoder layer 3 (split-K=4 for occupancy) ---
  kgemm3p<<<dim3(32, 1, 4), 256, 0, stream>>>(h2h, h2l, w3th, w3tl, nullptr, Cp, 128, 1024, 256,
                                              nullptr, nullptr, nullptr);
  kcombine<<<512, 256, 0, stream>>>((const float4*)Cp, b3, (float4*)y3, 131072, 131072, 4, 127);
  kbn_partial<<<dim3(1, 32), 128, 0, stream>>>(y3, ps, pq, 128);
  kbn_final<<<1, 128, 0, stream>>>(ps, pq, g3, bb3, scale, shift, 128, 32);
  kbn_apply_split4<<<512, 256, 0, stream>>>((const float4*)y3, scale, shift, (ushort4*)h3h,
                                            (ushort4*)h3l, 127);

  // --- lambda head + rate (fused epilogue) ---
  kgemm3p<<<dim3(32, 1), 256, 0, stream>>>(h3h, h3l, w4th, w4tl, b4, out_rate, 128, 128, 128,
                                           nullptr, nullptr, diag);

  // --- Poisson rsample ---
  kpoisson<<<2048, 256, 0, stream>>>(u, out_rate, out_samp, sb);

  // --- reconstruction ---
  kgemm<<<dim3(32, 8), 256, 0, stream>>>(sb, dct, out_xrec, 1024, 128);
}

// Round 7
// 249.368 us; speedup vs baseline: 2.4046x; 1.1046x over previous
//
#include <hip/hip_runtime.h>
#include <stdint.h>

// B=4096, IN=1024, L0=2048, L1=1024, H=128, NT=512, T=0.1, EPS=1e-5
// Round 7: round-6 base (275 us) + ONE lever: double-buffered LDS in the GEMM
// K-loops -> one __syncthreads per K-step (was two). Race-audit in journal.

typedef __attribute__((ext_vector_type(8))) __bf16 bf16x8;
typedef __attribute__((ext_vector_type(4))) float f32x4;

__device__ __forceinline__ unsigned short f2bf(float f) {
  unsigned int u = __float_as_uint(f);
  unsigned int r = (u + 0x7fffu + ((u >> 16) & 1u)) >> 16;  // RNE
  return (unsigned short)r;
}
__device__ __forceinline__ float bf2f(unsigned short h) {
  return __uint_as_float(((unsigned int)h) << 16);
}

__device__ __forceinline__ void gll16(const void* g, void* l) {
  __builtin_amdgcn_global_load_lds(
      (const __attribute__((address_space(1))) unsigned int*)g,
      (__attribute__((address_space(3))) unsigned int*)l, 16, 0, 0);
}

// ---------------- f32 -> split bf16 (hi, lo), 4 elems/thread ----------------
__global__ void kconvert_split4(const float4* __restrict__ in, ushort4* __restrict__ hi,
                                ushort4* __restrict__ lo, int n4) {
  int i = blockIdx.x * blockDim.x + threadIdx.x;
  if (i < n4) {
    float4 v = in[i];
    ushort4 h, l;
    h.x = f2bf(v.x); l.x = f2bf(v.x - bf2f(h.x));
    h.y = f2bf(v.y); l.y = f2bf(v.y - bf2f(h.y));
    h.z = f2bf(v.z); l.z = f2bf(v.z - bf2f(h.z));
    h.w = f2bf(v.w); l.w = f2bf(v.w - bf2f(h.w));
    hi[i] = h; lo[i] = l;
  }
}

// ---------------- transpose + split convert: in[R][C] f32 -> out[C][R] split bf16 ----------------
__global__ void ktranspose_split(const float* __restrict__ in, unsigned short* __restrict__ ohi,
                                 unsigned short* __restrict__ olo, int R, int C) {
  __shared__ unsigned short th[32][33];
  __shared__ unsigned short tl[32][33];
  int c0 = blockIdx.x * 32, r0 = blockIdx.y * 32;
  int tx = threadIdx.x & 31, ty = threadIdx.x >> 5;  // 32 x 8
#pragma unroll
  for (int i = 0; i < 32; i += 8) {
    float v = in[(size_t)(r0 + ty + i) * C + c0 + tx];
    unsigned short h = f2bf(v);
    th[ty + i][tx] = h;
    tl[ty + i][tx] = f2bf(v - bf2f(h));
  }
  __syncthreads();
#pragma unroll
  for (int i = 0; i < 32; i += 8) {
    ohi[(size_t)(c0 + ty + i) * R + r0 + tx] = th[tx][ty + i];
    olo[(size_t)(c0 + ty + i) * R + r0 + tx] = tl[tx][ty + i];
  }
}

// ---------------- split-bf16 3-pass MFMA GEMM, LDS double-buffered ----------------
// C[M][N] = (Ah+Al)[M][K] @ (Bh+Bl)[N][K]^T (+bias), dropping Al*Bl.
// grid = (M/128, N/128, splits). One __syncthreads per K-step:
//   iter kt: STAGE tile kt+1 -> buf[cur^1]; ds_read buf[cur]; MFMA; barrier.
// Safety: reads of buf[cur] covered by iter kt-1's barrier (vmcnt(0) drained);
// overwrite of buf[cur] happens in iter kt+1, after iter kt's barrier (reads done).
// LDS = 64KB static (sred aliased onto AsB after final barrier). 2 blocks/CU max.
__global__ __launch_bounds__(256) void kgemm3p(
    const unsigned short* __restrict__ Ah, const unsigned short* __restrict__ Al,
    const unsigned short* __restrict__ Bh, const unsigned short* __restrict__ Bl,
    const float* __restrict__ bias, float* __restrict__ C, int N, int K, int kLen,
    float* __restrict__ bnps, float* __restrict__ bnpq, const float* __restrict__ diag) {
  __shared__ unsigned short AsB[2][2][4096];  // [buf][hi|lo][128 rows x 32 k] 32KB
  __shared__ unsigned short BsB[2][2][4096];  // 32KB
  float (*sred)[2][128] = (float(*)[2][128])AsB;  // alias; used only after final barrier
  int tid = threadIdx.x;
  int lane = tid & 63;
  int wave = tid >> 6;
  int wm = wave >> 1, wn = wave & 1;
  int rowBase = blockIdx.x * 128;
  int colBase = blockIdx.y * 128;
  int kOff = blockIdx.z * kLen;
  C += (size_t)blockIdx.z * gridDim.x * 128 * N;  // split-K partial stripe

  f32x4 acc[4][4];
#pragma unroll
  for (int i = 0; i < 4; i++)
#pragma unroll
    for (int j = 0; j < 4; j++) acc[i][j] = (f32x4){0.f, 0.f, 0.f, 0.f};

  int r4 = tid >> 2;       // 0..63
  int kc = (tid & 3) * 8;  // 0,8,16,24
  int lr = lane & 15;
  int lk = (lane >> 4) * 8;

  const unsigned short* Ah0 = Ah + (size_t)(rowBase + r4) * K + kOff + kc;
  const unsigned short* Al0 = Al + (size_t)(rowBase + r4) * K + kOff + kc;
  const unsigned short* Bh0 = Bh + (size_t)(colBase + r4) * K + kOff + kc;
  const unsigned short* Bl0 = Bl + (size_t)(colBase + r4) * K + kOff + kc;
  size_t rstep = (size_t)64 * K;

  auto STAGE = [&](int k0, int buf) {
    char* aD = (char*)AsB + buf * 16384 + tid * 16;
    char* bD = (char*)BsB + buf * 16384 + tid * 16;
    gll16(Ah0 + k0, aD);        gll16(Ah0 + k0 + rstep, aD + 4096);
    gll16(Al0 + k0, aD + 8192); gll16(Al0 + k0 + rstep, aD + 12288);
    gll16(Bh0 + k0, bD);        gll16(Bh0 + k0 + rstep, bD + 4096);
    gll16(Bl0 + k0, bD + 8192); gll16(Bl0 + k0 + rstep, bD + 12288);
  };

  // prologue: stage tile 0 into buf 0
  STAGE(0, 0);
  __syncthreads();  // compiler drains vmcnt before barrier

  int nk = kLen >> 5;
  for (int kt = 0; kt < nk; ++kt) {
    int cur = kt & 1;
    // 1) issue next tile's staging into the other buffer — hides under reads+MFMA
    if (kt + 1 < nk) STAGE((kt + 1) << 5, cur ^ 1);

    // 2) LDS -> registers from current buffer
    bf16x8 ah[4], al[4], bh[4], bl[4];
    const unsigned short* Ac = &AsB[cur][0][0];
    const unsigned short* Bc = &BsB[cur][0][0];
#pragma unroll
    for (int mi = 0; mi < 4; mi++) {
      int ro = (wm * 64 + mi * 16 + lr) * 32 + lk;
      int co = (wn * 64 + mi * 16 + lr) * 32 + lk;
      ah[mi] = *(const bf16x8*)&Ac[ro];
      al[mi] = *(const bf16x8*)&Ac[4096 + ro];
      bh[mi] = *(const bf16x8*)&Bc[co];
      bl[mi] = *(const bf16x8*)&Bc[4096 + co];
    }

    // 3) 48 MFMAs (lgkmcnt inserted by compiler before first use)
#pragma unroll
    for (int mi = 0; mi < 4; mi++)
#pragma unroll
      for (int ni = 0; ni < 4; ni++) {
        acc[mi][ni] = __builtin_amdgcn_mfma_f32_16x16x32_bf16(ah[mi], bh[ni], acc[mi][ni], 0, 0, 0);
        acc[mi][ni] = __builtin_amdgcn_mfma_f32_16x16x32_bf16(ah[mi], bl[ni], acc[mi][ni], 0, 0, 0);
        acc[mi][ni] = __builtin_amdgcn_mfma_f32_16x16x32_bf16(al[mi], bh[ni], acc[mi][ni], 0, 0, 0);
      }
    __syncthreads();  // joins waves; drains this wave's stage (vmcnt) + reads (lgkm)
  }

  int lg = lane >> 4;
  if (diag) {
    // rate-mode epilogue: out = clip(|acc+bias| * diag[col], 1e-10, 1e7)
#pragma unroll
    for (int mi = 0; mi < 4; mi++)
#pragma unroll
      for (int ni = 0; ni < 4; ni++) {
        int col = colBase + wn * 64 + ni * 16 + lr;
        float bv = bias ? bias[col] : 0.0f;
        float dg = diag[col];
#pragma unroll
        for (int j = 0; j < 4; j++) {
          int row = rowBase + wm * 64 + mi * 16 + lg * 4 + j;
          float r = fabsf(acc[mi][ni][j] + bv) * dg;
          C[(size_t)row * N + col] = fminf(fmaxf(r, 1e-10f), 1e7f);
        }
      }
  } else {
    float s[4] = {0.f, 0.f, 0.f, 0.f}, q[4] = {0.f, 0.f, 0.f, 0.f};
#pragma unroll
    for (int mi = 0; mi < 4; mi++)
#pragma unroll
      for (int ni = 0; ni < 4; ni++) {
        int col = colBase + wn * 64 + ni * 16 + lr;
        float bv = bias ? bias[col] : 0.0f;
#pragma unroll
        for (int j = 0; j < 4; j++) {
          int row = rowBase + wm * 64 + mi * 16 + lg * 4 + j;
          float v = acc[mi][ni][j] + bv;
          C[(size_t)row * N + col] = v;
          s[ni] += v;
          q[ni] += v * v;
        }
      }
    if (bnps) {
      // reduce the 8 threads (lg x wm) covering each column; deterministic
#pragma unroll
      for (int ni = 0; ni < 4; ni++) {
        s[ni] += __shfl_xor(s[ni], 16); s[ni] += __shfl_xor(s[ni], 32);
        q[ni] += __shfl_xor(q[ni], 16); q[ni] += __shfl_xor(q[ni], 32);
      }
      if (lg == 0) {
#pragma unroll
        for (int ni = 0; ni < 4; ni++) {
          sred[wm][0][wn * 64 + ni * 16 + lr] = s[ni];
          sred[wm][1][wn * 64 + ni * 16 + lr] = q[ni];
        }
      }
      __syncthreads();
      if (tid < 128) {
        bnps[(size_t)blockIdx.x * N + colBase + tid] = sred[0][0][tid] + sred[1][0][tid];
        bnpq[(size_t)blockIdx.x * N + colBase + tid] = sred[0][1][tid] + sred[1][1][tid];
      }
    }
  }
}

// ---------------- single-pass bf16 GEMM (reconstruction), LDS double-buffered ----------------
__global__ __launch_bounds__(256) void kgemm(
    const unsigned short* __restrict__ A, const unsigned short* __restrict__ BT,
    float* __restrict__ C, int N, int K) {
  __shared__ unsigned short As2[2][4096];
  __shared__ unsigned short Bs2[2][4096];
  int tid = threadIdx.x;
  int lane = tid & 63;
  int wave = tid >> 6;
  int wm = wave >> 1, wn = wave & 1;
  int rowBase = blockIdx.x * 128;
  int colBase = blockIdx.y * 128;

  f32x4 acc[4][4];
#pragma unroll
  for (int i = 0; i < 4; i++)
#pragma unroll
    for (int j = 0; j < 4; j++) acc[i][j] = (f32x4){0.f, 0.f, 0.f, 0.f};

  int r4 = tid >> 2;
  int kc = (tid & 3) * 8;
  int lr = lane & 15;
  int lk = (lane >> 4) * 8;

  const unsigned short* A0 = A + (size_t)(rowBase + r4) * K + kc;
  const unsigned short* B0 = BT + (size_t)(colBase + r4) * K + kc;
  size_t rstep = (size_t)64 * K;

  auto STAGE = [&](int k0, int buf) {
    char* aD = (char*)As2 + buf * 8192 + tid * 16;
    char* bD = (char*)Bs2 + buf * 8192 + tid * 16;
    gll16(A0 + k0, aD); gll16(A0 + k0 + rstep, aD + 4096);
    gll16(B0 + k0, bD); gll16(B0 + k0 + rstep, bD + 4096);
  };

  STAGE(0, 0);
  __syncthreads();

  int nk = K >> 5;
  for (int kt = 0; kt < nk; ++kt) {
    int cur = kt & 1;
    if (kt + 1 < nk) STAGE((kt + 1) << 5, cur ^ 1);
    bf16x8 af[4], bfr[4];
#pragma unroll
    for (int mi = 0; mi < 4; mi++) {
      af[mi] = *(const bf16x8*)&As2[cur][(wm * 64 + mi * 16 + lr) * 32 + lk];
      bfr[mi] = *(const bf16x8*)&Bs2[cur][(wn * 64 + mi * 16 + lr) * 32 + lk];
    }
#pragma unroll
    for (int mi = 0; mi < 4; mi++)
#pragma unroll
      for (int ni = 0; ni < 4; ni++)
        acc[mi][ni] = __builtin_amdgcn_mfma_f32_16x16x32_bf16(af[mi], bfr[ni], acc[mi][ni], 0, 0, 0);
    __syncthreads();
  }

  int lg = lane >> 4;
#pragma unroll
  for (int mi = 0; mi < 4; mi++)
#pragma unroll
    for (int ni = 0; ni < 4; ni++) {
      int col = colBase + wn * 64 + ni * 16 + lr;
#pragma unroll
      for (int j = 0; j < 4; j++) {
        int row = rowBase + wm * 64 + mi * 16 + lg * 4 + j;
        C[(size_t)row * N + col] = acc[mi][ni][j];
      }
    }
}

// ---------------- BN partials for L3 (y3 is tiny) ----------------
__global__ void kbn_partial(const float* __restrict__ y, float* __restrict__ ps,
                            float* __restrict__ pq, int N) {
  int c = blockIdx.x * blockDim.x + threadIdx.x;
  int r0 = blockIdx.y * 128;
  float s = 0.f, q = 0.f;
  for (int r = r0; r < r0 + 128; ++r) {
    float v = y[(size_t)r * N + c];
    s += v;
    q += v * v;
  }
  ps[blockIdx.y * N + c] = s;
  pq[blockIdx.y * N + c] = q;
}

__global__ void kbn_final(const float* __restrict__ ps, const float* __restrict__ pq,
                          const float* __restrict__ g, const float* __restrict__ b,
                          float* __restrict__ scale, float* __restrict__ shift, int N,
                          int stripes) {
  int c = blockIdx.x * blockDim.x + threadIdx.x;
  if (c >= N) return;
  float s = 0.f, q = 0.f;
  for (int i = 0; i < stripes; ++i) {
    s += ps[i * N + c];
    q += pq[i * N + c];
  }
  float m = s * (1.0f / 4096.0f);
  float var = q * (1.0f / 4096.0f) - m * m;
  float sc = g[c] * rsqrtf(var + 1e-5f);
  scale[c] = sc;
  shift[c] = b[c] - m * sc;
}

// BN apply + ReLU + split-bf16 output, 4 elems/thread
__global__ void kbn_apply_split4(const float4* __restrict__ y, const float* __restrict__ scale,
                                 const float* __restrict__ shift, ushort4* __restrict__ hhi,
                                 ushort4* __restrict__ hlo, int mask) {
  int i = blockIdx.x * blockDim.x + threadIdx.x;
  int c0 = (i << 2) & mask;
  float4 v = y[i];
  ushort4 h, l;
  float t;
  t = v.x * scale[c0] + shift[c0];         t = t > 0.f ? t : 0.f; h.x = f2bf(t); l.x = f2bf(t - bf2f(h.x));
  t = v.y * scale[c0 + 1] + shift[c0 + 1]; t = t > 0.f ? t : 0.f; h.y = f2bf(t); l.y = f2bf(t - bf2f(h.y));
  t = v.z * scale[c0 + 2] + shift[c0 + 2]; t = t > 0.f ? t : 0.f; h.z = f2bf(t); l.z = f2bf(t - bf2f(h.z));
  t = v.w * scale[c0 + 3] + shift[c0 + 3]; t = t > 0.f ? t : 0.f; h.w = f2bf(t); l.w = f2bf(t - bf2f(h.w));
  hhi[i] = h;
  hlo[i] = l;
}

// ---------------- split-K combine for L3: y3 = sum_z Cp[z] + bias ----------------
__global__ void kcombine(const float4* __restrict__ Cp, const float* __restrict__ bias,
                         float4* __restrict__ y, int n4, int splitStride4, int splits, int mask) {
  int i = blockIdx.x * blockDim.x + threadIdx.x;
  if (i >= n4) return;
  int c0 = (i << 2) & mask;
  float4 a = Cp[i];
  for (int z = 1; z < splits; ++z) {
    float4 b = Cp[(size_t)z * splitStride4 + i];
    a.x += b.x; a.y += b.y; a.z += b.z; a.w += b.w;
  }
  a.x += bias[c0]; a.y += bias[c0 + 1]; a.z += bias[c0 + 2]; a.w += bias[c0 + 3];
  y[i] = a;
}

// ---------------- decoder normalization ----------------
__global__ void kdec(const float* __restrict__ dec_w, float* __restrict__ decode,
                     unsigned short* __restrict__ decT, float* __restrict__ diag) {
  int h = blockIdx.x, tx = threadIdx.x;
  __shared__ float red[256];
  float s = 0.f;
  for (int i = tx; i < 1024; i += 256) s += dec_w[h * 1024 + i];
  red[tx] = s;
  __syncthreads();
  for (int k = 128; k > 0; k >>= 1) {
    if (tx < k) red[tx] += red[tx + k];
    __syncthreads();
  }
  float d = fabsf(red[0]);
  if (tx == 0) diag[h] = d;
  float inv = 1.0f / d;
  for (int i = tx; i < 1024; i += 256) {
    float v = fabsf(dec_w[h * 1024 + i]) * inv;
    decode[h * 1024 + i] = v;
    decT[i * 128 + h] = f2bf(v);
  }
}

// ---------------- Poisson rsample with early exit ----------------
__global__ __launch_bounds__(256) void kpoisson(const float* __restrict__ u,
                                                const float* __restrict__ rate,
                                                float* __restrict__ samples,
                                                unsigned short* __restrict__ sb) {
  int tid = blockIdx.x * 256 + threadIdx.x;
  int h = tid & 127;
  int b = tid >> 7;
  float r = rate[tid];
  float inv = 1.0f / r;
  const float* up = u + (size_t)b * (512 * 128) + h;
  float t = 0.f, s = 0.f;
  for (int nt = 0; nt < 512; ++nt) {
    float uv = up[(size_t)nt * 128];
    t += (-__logf(uv)) * inv;
    float z = (t - 1.0f) * 10.0f;
    s += __frcp_rn(1.0f + __expf(z));
    if (t > 4.0f) break;
  }
  samples[tid] = s;
  sb[tid] = f2bf(s);
}

extern "C" void kernel_launch(void* const* d_in, const int* in_sizes, int n_in,
                              void* d_out, int out_size, void* d_ws, size_t ws_size,
                              hipStream_t stream) {
  const float* x = (const float*)d_in[0];
  const float* u = (const float*)d_in[1];
  const float* w1 = (const float*)d_in[2];
  const float* b1 = (const float*)d_in[3];
  const float* g1 = (const float*)d_in[4];
  const float* bb1 = (const float*)d_in[5];
  const float* w2 = (const float*)d_in[6];
  const float* b2 = (const float*)d_in[7];
  const float* g2 = (const float*)d_in[8];
  const float* bb2 = (const float*)d_in[9];
  const float* w3 = (const float*)d_in[10];
  const float* b3 = (const float*)d_in[11];
  const float* g3 = (const float*)d_in[12];
  const float* bb3 = (const float*)d_in[13];
  const float* w4 = (const float*)d_in[14];
  const float* b4 = (const float*)d_in[15];
  const float* dw = (const float*)d_in[16];

  float* out = (float*)d_out;
  float* out_xrec = out;            // [4096][1024]
  float* out_samp = out + 4194304;  // [4096][128]
  float* out_rate = out + 4718592;  // [4096][128]
  float* out_dec = out + 5242880;   // [128][1024]

  char* w = (char*)d_ws;
  unsigned short* xhi = (unsigned short*)w;  w += 8388608;   // [4096][1024]
  unsigned short* xlo = (unsigned short*)w;  w += 8388608;
  unsigned short* w1th = (unsigned short*)w; w += 4194304;   // [2048][1024]
  unsigned short* w1tl = (unsigned short*)w; w += 4194304;
  unsigned short* w2th = (unsigned short*)w; w += 4194304;   // [1024][2048]
  unsigned short* w2tl = (unsigned short*)w; w += 4194304;
  unsigned short* w3th = (unsigned short*)w; w += 262144;    // [128][1024]
  unsigned short* w3tl = (unsigned short*)w; w += 262144;
  unsigned short* w4th = (unsigned short*)w; w += 32768;     // [128][128]
  unsigned short* w4tl = (unsigned short*)w; w += 32768;
  float* y = (float*)w;             w += 33554432;           // y1 [4096][2048], reused as y2
  unsigned short* h1h = (unsigned short*)w; w += 16777216;   // [4096][2048]
  unsigned short* h1l = (unsigned short*)w; w += 16777216;
  unsigned short* h2h = (unsigned short*)w; w += 8388608;    // [4096][1024]
  unsigned short* h2l = (unsigned short*)w; w += 8388608;
  unsigned short* h3h = (unsigned short*)w; w += 1048576;    // [4096][128]
  unsigned short* h3l = (unsigned short*)w; w += 1048576;
  float* y3 = (float*)w;            w += 2097152;            // [4096][128]
  float* Cp = (float*)w;            w += 8388608;            // split-K partials [4][4096][128]
  unsigned short* sb = (unsigned short*)w; w += 1048576;     // samples bf16
  unsigned short* dct = (unsigned short*)w; w += 262144;     // decode^T bf16 [1024][128]
  float* diag = (float*)w;          w += 1024;
  float* ps = (float*)w;            w += 262144;             // [<=32][N<=2048]
  float* pq = (float*)w;            w += 262144;
  float* scale = (float*)w;         w += 8192;
  float* shift = (float*)w;         w += 8192;

  // --- prep ---
  kconvert_split4<<<4096, 256, 0, stream>>>((const float4*)x, (ushort4*)xhi, (ushort4*)xlo, 1048576);
  ktranspose_split<<<dim3(64, 32), 256, 0, stream>>>(w1, w1th, w1tl, 1024, 2048);
  ktranspose_split<<<dim3(32, 64), 256, 0, stream>>>(w2, w2th, w2tl, 2048, 1024);
  ktranspose_split<<<dim3(4, 32), 256, 0, stream>>>(w3, w3th, w3tl, 1024, 128);
  ktranspose_split<<<dim3(4, 4), 256, 0, stream>>>(w4, w4th, w4tl, 128, 128);
  kdec<<<128, 256, 0, stream>>>(dw, out_dec, dct, diag);

  // --- encoder layer 1 (BN partials fused into GEMM epilogue) ---
  kgemm3p<<<dim3(32, 16), 256, 0, stream>>>(xhi, xlo, w1th, w1tl, b1, y, 2048, 1024, 1024,
                                            ps, pq, nullptr);
  kbn_final<<<8, 256, 0, stream>>>(ps, pq, g1, bb1, scale, shift, 2048, 32);
  kbn_apply_split4<<<8192, 256, 0, stream>>>((const float4*)y, scale, shift, (ushort4*)h1h,
                                             (ushort4*)h1l, 2047);

  // --- encoder layer 2 ---
  kgemm3p<<<dim3(32, 8), 256, 0, stream>>>(h1h, h1l, w2th, w2tl, b2, y, 1024, 2048, 2048,
                                           ps, pq, nullptr);
  kbn_final<<<4, 256, 0, stream>>>(ps, pq, g2, bb2, scale, shift, 1024, 32);
  kbn_apply_split4<<<4096, 256, 0, stream>>>((const float4*)y, scale, shift, (ushort4*)h2h,
                                             (ushort4*)h2l, 1023);

  // --- encoder layer 3 (split-K=4 for occupancy) ---
  kgemm3p<<<dim3(32, 1, 4), 256, 0, stream>>>(h2h, h2l, w3th, w3tl, nullptr, Cp, 128, 1024, 256,
                                              nullptr, nullptr, nullptr);
  kcombine<<<512, 256, 0, stream>>>((const float4*)Cp, b3, (float4*)y3, 131072, 131072, 4, 127);
  kbn_partial<<<dim3(1, 32), 128, 0, stream>>>(y3, ps, pq, 128);
  kbn_final<<<1, 128, 0, stream>>>(ps, pq, g3, bb3, scale, shift, 128, 32);
  kbn_apply_split4<<<512, 256, 0, stream>>>((const float4*)y3, scale, shift, (ushort4*)h3h,
                                            (ushort4*)h3l, 127);

  // --- lambda head + rate (fused epilogue) ---
  kgemm3p<<<dim3(32, 1), 256, 0, stream>>>(h3h, h3l, w4th, w4tl, b4, out_rate, 128, 128, 128,
                                           nullptr, nullptr, diag);

  // --- Poisson rsample ---
  kpoisson<<<2048, 256, 0, stream>>>(u, out_rate, out_samp, sb);

  // --- reconstruction ---
  kgemm<<<dim3(32, 8), 256, 0, stream>>>(sb, dct, out_xrec, 1024, 128);
}

// Round 8
// 240.368 us; speedup vs baseline: 2.4946x; 1.0374x over previous
//
#include <hip/hip_runtime.h>
#include <stdint.h>

// B=4096, IN=1024, L0=2048, L1=1024, H=128, NT=512, T=0.1, EPS=1e-5
// Round 8: round-7 base (249 us) + launch consolidation ONLY:
//   - kprep fuses {convert_split, 4x transpose_split, kdec} into one launch
//   - kcombine_partial fuses L3 {split-K combine, BN partial} into one launch
// GEMM kernels byte-identical to round 7. All f32 summation orders preserved.

typedef __attribute__((ext_vector_type(8))) __bf16 bf16x8;
typedef __attribute__((ext_vector_type(4))) float f32x4;

__device__ __forceinline__ unsigned short f2bf(float f) {
  unsigned int u = __float_as_uint(f);
  unsigned int r = (u + 0x7fffu + ((u >> 16) & 1u)) >> 16;  // RNE
  return (unsigned short)r;
}
__device__ __forceinline__ float bf2f(unsigned short h) {
  return __uint_as_float(((unsigned int)h) << 16);
}

__device__ __forceinline__ void gll16(const void* g, void* l) {
  __builtin_amdgcn_global_load_lds(
      (const __attribute__((address_space(1))) unsigned int*)g,
      (__attribute__((address_space(3))) unsigned int*)l, 16, 0, 0);
}

// ---------------- transpose + split convert tile (device body) ----------------
__device__ __forceinline__ void tsplit_tile(const float* __restrict__ in,
                                            unsigned short* __restrict__ ohi,
                                            unsigned short* __restrict__ olo,
                                            int R, int C, int bx, int by, int tid) {
  __shared__ unsigned short th[32][33];
  __shared__ unsigned short tl[32][33];
  int c0 = bx * 32, r0 = by * 32;
  int tx = tid & 31, ty = tid >> 5;  // 32 x 8
#pragma unroll
  for (int i = 0; i < 32; i += 8) {
    float v = in[(size_t)(r0 + ty + i) * C + c0 + tx];
    unsigned short h = f2bf(v);
    th[ty + i][tx] = h;
    tl[ty + i][tx] = f2bf(v - bf2f(h));
  }
  __syncthreads();
#pragma unroll
  for (int i = 0; i < 32; i += 8) {
    ohi[(size_t)(c0 + ty + i) * R + r0 + tx] = th[tx][ty + i];
    olo[(size_t)(c0 + ty + i) * R + r0 + tx] = tl[tx][ty + i];
  }
}

// ---------------- fused prep: convert x, transpose w1..w4, decoder norm ----------------
// blockIdx.x ranges: [0,4096) convert; [4096,6144) w1; [6144,8192) w2;
// [8192,8320) w3; [8320,8336) w4; [8336,8464) kdec.
__global__ void kprep(const float4* __restrict__ x4, ushort4* __restrict__ xhi4,
                      ushort4* __restrict__ xlo4,
                      const float* __restrict__ w1, unsigned short* __restrict__ w1th,
                      unsigned short* __restrict__ w1tl,
                      const float* __restrict__ w2, unsigned short* __restrict__ w2th,
                      unsigned short* __restrict__ w2tl,
                      const float* __restrict__ w3, unsigned short* __restrict__ w3th,
                      unsigned short* __restrict__ w3tl,
                      const float* __restrict__ w4, unsigned short* __restrict__ w4th,
                      unsigned short* __restrict__ w4tl,
                      const float* __restrict__ dw, float* __restrict__ decode,
                      unsigned short* __restrict__ decT, float* __restrict__ diag) {
  int z = blockIdx.x;
  int tid = threadIdx.x;
  if (z < 4096) {
    int i = z * 256 + tid;
    float4 v = x4[i];
    ushort4 h, l;
    h.x = f2bf(v.x); l.x = f2bf(v.x - bf2f(h.x));
    h.y = f2bf(v.y); l.y = f2bf(v.y - bf2f(h.y));
    h.z = f2bf(v.z); l.z = f2bf(v.z - bf2f(h.z));
    h.w = f2bf(v.w); l.w = f2bf(v.w - bf2f(h.w));
    xhi4[i] = h; xlo4[i] = l;
  } else if (z < 6144) {
    int zz = z - 4096;
    tsplit_tile(w1, w1th, w1tl, 1024, 2048, zz & 63, zz >> 6, tid);
  } else if (z < 8192) {
    int zz = z - 6144;
    tsplit_tile(w2, w2th, w2tl, 2048, 1024, zz & 31, zz >> 5, tid);
  } else if (z < 8320) {
    int zz = z - 8192;
    tsplit_tile(w3, w3th, w3tl, 1024, 128, zz & 3, zz >> 2, tid);
  } else if (z < 8336) {
    int zz = z - 8320;
    tsplit_tile(w4, w4th, w4tl, 128, 128, zz & 3, zz >> 2, tid);
  } else {
    int h = z - 8336;
    __shared__ float red[256];
    float s = 0.f;
    for (int i = tid; i < 1024; i += 256) s += dw[h * 1024 + i];
    red[tid] = s;
    __syncthreads();
    for (int k = 128; k > 0; k >>= 1) {
      if (tid < k) red[tid] += red[tid + k];
      __syncthreads();
    }
    float d = fabsf(red[0]);
    if (tid == 0) diag[h] = d;
    float inv = 1.0f / d;
    for (int i = tid; i < 1024; i += 256) {
      float v = fabsf(dw[h * 1024 + i]) * inv;
      decode[h * 1024 + i] = v;
      decT[i * 128 + h] = f2bf(v);
    }
  }
}

// ---------------- split-bf16 3-pass MFMA GEMM, LDS double-buffered ----------------
// C[M][N] = (Ah+Al)[M][K] @ (Bh+Bl)[N][K]^T (+bias), dropping Al*Bl.
// grid = (M/128, N/128, splits). One __syncthreads per K-step:
//   iter kt: STAGE tile kt+1 -> buf[cur^1]; ds_read buf[cur]; MFMA; barrier.
__global__ __launch_bounds__(256) void kgemm3p(
    const unsigned short* __restrict__ Ah, const unsigned short* __restrict__ Al,
    const unsigned short* __restrict__ Bh, const unsigned short* __restrict__ Bl,
    const float* __restrict__ bias, float* __restrict__ C, int N, int K, int kLen,
    float* __restrict__ bnps, float* __restrict__ bnpq, const float* __restrict__ diag) {
  __shared__ unsigned short AsB[2][2][4096];  // [buf][hi|lo][128 rows x 32 k] 32KB
  __shared__ unsigned short BsB[2][2][4096];  // 32KB
  float (*sred)[2][128] = (float(*)[2][128])AsB;  // alias; used only after final barrier
  int tid = threadIdx.x;
  int lane = tid & 63;
  int wave = tid >> 6;
  int wm = wave >> 1, wn = wave & 1;
  int rowBase = blockIdx.x * 128;
  int colBase = blockIdx.y * 128;
  int kOff = blockIdx.z * kLen;
  C += (size_t)blockIdx.z * gridDim.x * 128 * N;  // split-K partial stripe

  f32x4 acc[4][4];
#pragma unroll
  for (int i = 0; i < 4; i++)
#pragma unroll
    for (int j = 0; j < 4; j++) acc[i][j] = (f32x4){0.f, 0.f, 0.f, 0.f};

  int r4 = tid >> 2;       // 0..63
  int kc = (tid & 3) * 8;  // 0,8,16,24
  int lr = lane & 15;
  int lk = (lane >> 4) * 8;

  const unsigned short* Ah0 = Ah + (size_t)(rowBase + r4) * K + kOff + kc;
  const unsigned short* Al0 = Al + (size_t)(rowBase + r4) * K + kOff + kc;
  const unsigned short* Bh0 = Bh + (size_t)(colBase + r4) * K + kOff + kc;
  const unsigned short* Bl0 = Bl + (size_t)(colBase + r4) * K + kOff + kc;
  size_t rstep = (size_t)64 * K;

  auto STAGE = [&](int k0, int buf) {
    char* aD = (char*)AsB + buf * 16384 + tid * 16;
    char* bD = (char*)BsB + buf * 16384 + tid * 16;
    gll16(Ah0 + k0, aD);        gll16(Ah0 + k0 + rstep, aD + 4096);
    gll16(Al0 + k0, aD + 8192); gll16(Al0 + k0 + rstep, aD + 12288);
    gll16(Bh0 + k0, bD);        gll16(Bh0 + k0 + rstep, bD + 4096);
    gll16(Bl0 + k0, bD + 8192); gll16(Bl0 + k0 + rstep, bD + 12288);
  };

  // prologue: stage tile 0 into buf 0
  STAGE(0, 0);
  __syncthreads();  // compiler drains vmcnt before barrier

  int nk = kLen >> 5;
  for (int kt = 0; kt < nk; ++kt) {
    int cur = kt & 1;
    // 1) issue next tile's staging into the other buffer — hides under reads+MFMA
    if (kt + 1 < nk) STAGE((kt + 1) << 5, cur ^ 1);

    // 2) LDS -> registers from current buffer
    bf16x8 ah[4], al[4], bh[4], bl[4];
    const unsigned short* Ac = &AsB[cur][0][0];
    const unsigned short* Bc = &BsB[cur][0][0];
#pragma unroll
    for (int mi = 0; mi < 4; mi++) {
      int ro = (wm * 64 + mi * 16 + lr) * 32 + lk;
      int co = (wn * 64 + mi * 16 + lr) * 32 + lk;
      ah[mi] = *(const bf16x8*)&Ac[ro];
      al[mi] = *(const bf16x8*)&Ac[4096 + ro];
      bh[mi] = *(const bf16x8*)&Bc[co];
      bl[mi] = *(const bf16x8*)&Bc[4096 + co];
    }

    // 3) 48 MFMAs (lgkmcnt inserted by compiler before first use)
#pragma unroll
    for (int mi = 0; mi < 4; mi++)
#pragma unroll
      for (int ni = 0; ni < 4; ni++) {
        acc[mi][ni] = __builtin_amdgcn_mfma_f32_16x16x32_bf16(ah[mi], bh[ni], acc[mi][ni], 0, 0, 0);
        acc[mi][ni] = __builtin_amdgcn_mfma_f32_16x16x32_bf16(ah[mi], bl[ni], acc[mi][ni], 0, 0, 0);
        acc[mi][ni] = __builtin_amdgcn_mfma_f32_16x16x32_bf16(al[mi], bh[ni], acc[mi][ni], 0, 0, 0);
      }
    __syncthreads();  // joins waves; drains this wave's stage (vmcnt) + reads (lgkm)
  }

  int lg = lane >> 4;
  if (diag) {
    // rate-mode epilogue: out = clip(|acc+bias| * diag[col], 1e-10, 1e7)
#pragma unroll
    for (int mi = 0; mi < 4; mi++)
#pragma unroll
      for (int ni = 0; ni < 4; ni++) {
        int col = colBase + wn * 64 + ni * 16 + lr;
        float bv = bias ? bias[col] : 0.0f;
        float dg = diag[col];
#pragma unroll
        for (int j = 0; j < 4; j++) {
          int row = rowBase + wm * 64 + mi * 16 + lg * 4 + j;
          float r = fabsf(acc[mi][ni][j] + bv) * dg;
          C[(size_t)row * N + col] = fminf(fmaxf(r, 1e-10f), 1e7f);
        }
      }
  } else {
    float s[4] = {0.f, 0.f, 0.f, 0.f}, q[4] = {0.f, 0.f, 0.f, 0.f};
#pragma unroll
    for (int mi = 0; mi < 4; mi++)
#pragma unroll
      for (int ni = 0; ni < 4; ni++) {
        int col = colBase + wn * 64 + ni * 16 + lr;
        float bv = bias ? bias[col] : 0.0f;
#pragma unroll
        for (int j = 0; j < 4; j++) {
          int row = rowBase + wm * 64 + mi * 16 + lg * 4 + j;
          float v = acc[mi][ni][j] + bv;
          C[(size_t)row * N + col] = v;
          s[ni] += v;
          q[ni] += v * v;
        }
      }
    if (bnps) {
      // reduce the 8 threads (lg x wm) covering each column; deterministic
#pragma unroll
      for (int ni = 0; ni < 4; ni++) {
        s[ni] += __shfl_xor(s[ni], 16); s[ni] += __shfl_xor(s[ni], 32);
        q[ni] += __shfl_xor(q[ni], 16); q[ni] += __shfl_xor(q[ni], 32);
      }
      if (lg == 0) {
#pragma unroll
        for (int ni = 0; ni < 4; ni++) {
          sred[wm][0][wn * 64 + ni * 16 + lr] = s[ni];
          sred[wm][1][wn * 64 + ni * 16 + lr] = q[ni];
        }
      }
      __syncthreads();
      if (tid < 128) {
        bnps[(size_t)blockIdx.x * N + colBase + tid] = sred[0][0][tid] + sred[1][0][tid];
        bnpq[(size_t)blockIdx.x * N + colBase + tid] = sred[0][1][tid] + sred[1][1][tid];
      }
    }
  }
}

// ---------------- single-pass bf16 GEMM (reconstruction), LDS double-buffered ----------------
__global__ __launch_bounds__(256) void kgemm(
    const unsigned short* __restrict__ A, const unsigned short* __restrict__ BT,
    float* __restrict__ C, int N, int K) {
  __shared__ unsigned short As2[2][4096];
  __shared__ unsigned short Bs2[2][4096];
  int tid = threadIdx.x;
  int lane = tid & 63;
  int wave = tid >> 6;
  int wm = wave >> 1, wn = wave & 1;
  int rowBase = blockIdx.x * 128;
  int colBase = blockIdx.y * 128;

  f32x4 acc[4][4];
#pragma unroll
  for (int i = 0; i < 4; i++)
#pragma unroll
    for (int j = 0; j < 4; j++) acc[i][j] = (f32x4){0.f, 0.f, 0.f, 0.f};

  int r4 = tid >> 2;
  int kc = (tid & 3) * 8;
  int lr = lane & 15;
  int lk = (lane >> 4) * 8;

  const unsigned short* A0 = A + (size_t)(rowBase + r4) * K + kc;
  const unsigned short* B0 = BT + (size_t)(colBase + r4) * K + kc;
  size_t rstep = (size_t)64 * K;

  auto STAGE = [&](int k0, int buf) {
    char* aD = (char*)As2 + buf * 8192 + tid * 16;
    char* bD = (char*)Bs2 + buf * 8192 + tid * 16;
    gll16(A0 + k0, aD); gll16(A0 + k0 + rstep, aD + 4096);
    gll16(B0 + k0, bD); gll16(B0 + k0 + rstep, bD + 4096);
  };

  STAGE(0, 0);
  __syncthreads();

  int nk = K >> 5;
  for (int kt = 0; kt < nk; ++kt) {
    int cur = kt & 1;
    if (kt + 1 < nk) STAGE((kt + 1) << 5, cur ^ 1);
    bf16x8 af[4], bfr[4];
#pragma unroll
    for (int mi = 0; mi < 4; mi++) {
      af[mi] = *(const bf16x8*)&As2[cur][(wm * 64 + mi * 16 + lr) * 32 + lk];
      bfr[mi] = *(const bf16x8*)&Bs2[cur][(wn * 64 + mi * 16 + lr) * 32 + lk];
    }
#pragma unroll
    for (int mi = 0; mi < 4; mi++)
#pragma unroll
      for (int ni = 0; ni < 4; ni++)
        acc[mi][ni] = __builtin_amdgcn_mfma_f32_16x16x32_bf16(af[mi], bfr[ni], acc[mi][ni], 0, 0, 0);
    __syncthreads();
  }

  int lg = lane >> 4;
#pragma unroll
  for (int mi = 0; mi < 4; mi++)
#pragma unroll
    for (int ni = 0; ni < 4; ni++) {
      int col = colBase + wn * 64 + ni * 16 + lr;
#pragma unroll
      for (int j = 0; j < 4; j++) {
        int row = rowBase + wm * 64 + mi * 16 + lg * 4 + j;
        C[(size_t)row * N + col] = acc[mi][ni][j];
      }
    }
}

// ---- fused L3 split-K combine + bias + BN column partials (order matches r7) ----
// 32 blocks x 128 threads; thread = column c; block = 128-row stripe.
__global__ void kcombine_partial(const float* __restrict__ Cp, const float* __restrict__ bias,
                                 float* __restrict__ y, float* __restrict__ ps,
                                 float* __restrict__ pq) {
  int c = threadIdx.x;
  int r0 = blockIdx.x * 128;
  float bv = bias[c];
  float s = 0.f, q = 0.f;
  for (int r = r0; r < r0 + 128; ++r) {
    float a = Cp[(size_t)r * 128 + c];
    a += Cp[524288 + (size_t)r * 128 + c];
    a += Cp[1048576 + (size_t)r * 128 + c];
    a += Cp[1572864 + (size_t)r * 128 + c];
    a += bv;
    y[(size_t)r * 128 + c] = a;
    s += a;
    q += a * a;
  }
  ps[blockIdx.x * 128 + c] = s;
  pq[blockIdx.x * 128 + c] = q;
}

__global__ void kbn_final(const float* __restrict__ ps, const float* __restrict__ pq,
                          const float* __restrict__ g, const float* __restrict__ b,
                          float* __restrict__ scale, float* __restrict__ shift, int N,
                          int stripes) {
  int c = blockIdx.x * blockDim.x + threadIdx.x;
  if (c >= N) return;
  float s = 0.f, q = 0.f;
  for (int i = 0; i < stripes; ++i) {
    s += ps[i * N + c];
    q += pq[i * N + c];
  }
  float m = s * (1.0f / 4096.0f);
  float var = q * (1.0f / 4096.0f) - m * m;
  float sc = g[c] * rsqrtf(var + 1e-5f);
  scale[c] = sc;
  shift[c] = b[c] - m * sc;
}

// BN apply + ReLU + split-bf16 output, 4 elems/thread
__global__ void kbn_apply_split4(const float4* __restrict__ y, const float* __restrict__ scale,
                                 const float* __restrict__ shift, ushort4* __restrict__ hhi,
                                 ushort4* __restrict__ hlo, int mask) {
  int i = blockIdx.x * blockDim.x + threadIdx.x;
  int c0 = (i << 2) & mask;
  float4 v = y[i];
  ushort4 h, l;
  float t;
  t = v.x * scale[c0] + shift[c0];         t = t > 0.f ? t : 0.f; h.x = f2bf(t); l.x = f2bf(t - bf2f(h.x));
  t = v.y * scale[c0 + 1] + shift[c0 + 1]; t = t > 0.f ? t : 0.f; h.y = f2bf(t); l.y = f2bf(t - bf2f(h.y));
  t = v.z * scale[c0 + 2] + shift[c0 + 2]; t = t > 0.f ? t : 0.f; h.z = f2bf(t); l.z = f2bf(t - bf2f(h.z));
  t = v.w * scale[c0 + 3] + shift[c0 + 3]; t = t > 0.f ? t : 0.f; h.w = f2bf(t); l.w = f2bf(t - bf2f(h.w));
  hhi[i] = h;
  hlo[i] = l;
}

// ---------------- Poisson rsample with early exit ----------------
__global__ __launch_bounds__(256) void kpoisson(const float* __restrict__ u,
                                                const float* __restrict__ rate,
                                                float* __restrict__ samples,
                                                unsigned short* __restrict__ sb) {
  int tid = blockIdx.x * 256 + threadIdx.x;
  int h = tid & 127;
  int b = tid >> 7;
  float r = rate[tid];
  float inv = 1.0f / r;
  const float* up = u + (size_t)b * (512 * 128) + h;
  float t = 0.f, s = 0.f;
  for (int nt = 0; nt < 512; ++nt) {
    float uv = up[(size_t)nt * 128];
    t += (-__logf(uv)) * inv;
    float z = (t - 1.0f) * 10.0f;
    s += __frcp_rn(1.0f + __expf(z));
    if (t > 4.0f) break;
  }
  samples[tid] = s;
  sb[tid] = f2bf(s);
}

extern "C" void kernel_launch(void* const* d_in, const int* in_sizes, int n_in,
                              void* d_out, int out_size, void* d_ws, size_t ws_size,
                              hipStream_t stream) {
  const float* x = (const float*)d_in[0];
  const float* u = (const float*)d_in[1];
  const float* w1 = (const float*)d_in[2];
  const float* b1 = (const float*)d_in[3];
  const float* g1 = (const float*)d_in[4];
  const float* bb1 = (const float*)d_in[5];
  const float* w2 = (const float*)d_in[6];
  const float* b2 = (const float*)d_in[7];
  const float* g2 = (const float*)d_in[8];
  const float* bb2 = (const float*)d_in[9];
  const float* w3 = (const float*)d_in[10];
  const float* b3 = (const float*)d_in[11];
  const float* g3 = (const float*)d_in[12];
  const float* bb3 = (const float*)d_in[13];
  const float* w4 = (const float*)d_in[14];
  const float* b4 = (const float*)d_in[15];
  const float* dw = (const float*)d_in[16];

  float* out = (float*)d_out;
  float* out_xrec = out;            // [4096][1024]
  float* out_samp = out + 4194304;  // [4096][128]
  float* out_rate = out + 4718592;  // [4096][128]
  float* out_dec = out + 5242880;   // [128][1024]

  char* w = (char*)d_ws;
  unsigned short* xhi = (unsigned short*)w;  w += 8388608;   // [4096][1024]
  unsigned short* xlo = (unsigned short*)w;  w += 8388608;
  unsigned short* w1th = (unsigned short*)w; w += 4194304;   // [2048][1024]
  unsigned short* w1tl = (unsigned short*)w; w += 4194304;
  unsigned short* w2th = (unsigned short*)w; w += 4194304;   // [1024][2048]
  unsigned short* w2tl = (unsigned short*)w; w += 4194304;
  unsigned short* w3th = (unsigned short*)w; w += 262144;    // [128][1024]
  unsigned short* w3tl = (unsigned short*)w; w += 262144;
  unsigned short* w4th = (unsigned short*)w; w += 32768;     // [128][128]
  unsigned short* w4tl = (unsigned short*)w; w += 32768;
  float* y = (float*)w;             w += 33554432;           // y1 [4096][2048], reused as y2
  unsigned short* h1h = (unsigned short*)w; w += 16777216;   // [4096][2048]
  unsigned short* h1l = (unsigned short*)w; w += 16777216;
  unsigned short* h2h = (unsigned short*)w; w += 8388608;    // [4096][1024]
  unsigned short* h2l = (unsigned short*)w; w += 8388608;
  unsigned short* h3h = (unsigned short*)w; w += 1048576;    // [4096][128]
  unsigned short* h3l = (unsigned short*)w; w += 1048576;
  float* y3 = (float*)w;            w += 2097152;            // [4096][128]
  float* Cp = (float*)w;            w += 8388608;            // split-K partials [4][4096][128]
  unsigned short* sb = (unsigned short*)w; w += 1048576;     // samples bf16
  unsigned short* dct = (unsigned short*)w; w += 262144;     // decode^T bf16 [1024][128]
  float* diag = (float*)w;          w += 1024;
  float* ps = (float*)w;            w += 262144;             // [<=32][N<=2048]
  float* pq = (float*)w;            w += 262144;
  float* scale = (float*)w;         w += 8192;
  float* shift = (float*)w;         w += 8192;

  // --- fused prep (was 6 launches) ---
  kprep<<<8464, 256, 0, stream>>>((const float4*)x, (ushort4*)xhi, (ushort4*)xlo,
                                  w1, w1th, w1tl, w2, w2th, w2tl, w3, w3th, w3tl,
                                  w4, w4th, w4tl, dw, out_dec, dct, diag);

  // --- encoder layer 1 (BN partials fused into GEMM epilogue) ---
  kgemm3p<<<dim3(32, 16), 256, 0, stream>>>(xhi, xlo, w1th, w1tl, b1, y, 2048, 1024, 1024,
                                            ps, pq, nullptr);
  kbn_final<<<8, 256, 0, stream>>>(ps, pq, g1, bb1, scale, shift, 2048, 32);
  kbn_apply_split4<<<8192, 256, 0, stream>>>((const float4*)y, scale, shift, (ushort4*)h1h,
                                             (ushort4*)h1l, 2047);

  // --- encoder layer 2 ---
  kgemm3p<<<dim3(32, 8), 256, 0, stream>>>(h1h, h1l, w2th, w2tl, b2, y, 1024, 2048, 2048,
                                           ps, pq, nullptr);
  kbn_final<<<4, 256, 0, stream>>>(ps, pq, g2, bb2, scale, shift, 1024, 32);
  kbn_apply_split4<<<4096, 256, 0, stream>>>((const float4*)y, scale, shift, (ushort4*)h2h,
                                             (ushort4*)h2l, 1023);

  // --- encoder layer 3 (split-K=4) ---
  kgemm3p<<<dim3(32, 1, 4), 256, 0, stream>>>(h2h, h2l, w3th, w3tl, nullptr, Cp, 128, 1024, 256,
                                              nullptr, nullptr, nullptr);
  kcombine_partial<<<32, 128, 0, stream>>>(Cp, b3, y3, ps, pq);
  kbn_final<<<1, 128, 0, stream>>>(ps, pq, g3, bb3, scale, shift, 128, 32);
  kbn_apply_split4<<<512, 256, 0, stream>>>((const float4*)y3, scale, shift, (ushort4*)h3h,
                                            (ushort4*)h3l, 127);

  // --- lambda head + rate (fused epilogue) ---
  kgemm3p<<<dim3(32, 1), 256, 0, stream>>>(h3h, h3l, w4th, w4tl, b4, out_rate, 128, 128, 128,
                                           nullptr, nullptr, diag);

  // --- Poisson rsample ---
  kpoisson<<<2048, 256, 0, stream>>>(u, out_rate, out_samp, sb);

  // --- reconstruction ---
  kgemm<<<dim3(32, 8), 256, 0, stream>>>(sb, dct, out_xrec, 1024, 128);
}